// Round 1
// baseline (1319.291 us; speedup 1.0000x reference)
//
#include <hip/hip_runtime.h>
#include <math.h>

#define Nn 4
#define Cc 64
#define Hh 192
#define Ww 192
#define HW (Hh*Ww)          // 36864
#define PIXBLK 144          // HW/256
#define D4c 16

// ---------------- kernel 1: global average pool ----------------
__global__ void k_gap(const float* __restrict__ x, float* __restrict__ fp){
    int nc = blockIdx.x;                     // 0..255  (n*64+c)
    const float* p = x + (size_t)nc*HW;
    float s = 0.f;
    for(int i=threadIdx.x;i<HW;i+=256) s += p[i];
    for(int o=32;o>0;o>>=1) s += __shfl_down(s,o);
    __shared__ float sm[4];
    int wid = threadIdx.x>>6, ln = threadIdx.x&63;
    if(ln==0) sm[wid]=s;
    __syncthreads();
    if(threadIdx.x==0) fp[nc] = (sm[0]+sm[1]+sm[2]+sm[3]) / (float)HW;
}

// ---------------- kernel 2: dynamic filter (matvec + GN + softmax) ----------------
__global__ void k_filter(const float* __restrict__ fp, const float* __restrict__ wf,
                         const float* __restrict__ gg, const float* __restrict__ gb,
                         float* __restrict__ fsm){
    int n = blockIdx.x;
    __shared__ float sfp[64];
    __shared__ float sfw[576];
    __shared__ float gstat[8];
    int t = threadIdx.x;                       // 0..575
    if(t<64) sfp[t] = fp[n*64+t];
    __syncthreads();
    const float* wr = wf + (size_t)t*64;
    float acc = 0.f;
    #pragma unroll 8
    for(int k=0;k<64;k++) acc += sfp[k]*wr[k];
    sfw[t] = acc;
    __syncthreads();
    if(t<4){
        float s=0.f,s2=0.f;
        for(int i=0;i<144;i++){ float v=sfw[t*144+i]; s+=v; s2+=v*v; }
        float m = s/144.f;
        gstat[t*2]   = m;
        gstat[t*2+1] = s2/144.f - m*m;
    }
    __syncthreads();
    int g = t/144;
    float m = gstat[g*2], var = gstat[g*2+1];
    float z = (acc-m)*rsqrtf(var+1e-5f)*gg[t] + gb[t];
    sfw[t] = z;
    __syncthreads();
    if(t<64){
        float mx = -1e30f;
        for(int j=0;j<9;j++) mx = fmaxf(mx, sfw[t*9+j]);
        float e[9]; float se=0.f;
        for(int j=0;j<9;j++){ e[j]=expf(sfw[t*9+j]-mx); se+=e[j]; }
        float inv = 1.f/se;
        for(int j=0;j<9;j++) fsm[((size_t)n*64+t)*9+j] = e[j]*inv;
    }
}

// ---------------- kernel 3: low/high + conv1x1(64->16)+PReLU ----------------
__global__ void k_lowhigh(const float* __restrict__ x, const float* __restrict__ fsm,
                          const float* __restrict__ w1, const float* __restrict__ b1,
                          const float* __restrict__ a1p,
                          float* __restrict__ high, float* __restrict__ y1){
    int bid = blockIdx.x;
    int n = bid/PIXBLK;
    int pix = (bid%PIXBLK)*256 + threadIdx.x;
    int h = pix/Ww, w = pix%Ww;
    __shared__ float sf[64*9];
    __shared__ float sw[16*64];
    __shared__ float sb[16];
    for(int i=threadIdx.x;i<576;i+=256) sf[i] = fsm[(size_t)n*576+i];
    for(int i=threadIdx.x;i<1024;i+=256) sw[i] = w1[i];
    if(threadIdx.x<16) sb[threadIdx.x] = b1[threadIdx.x];
    __syncthreads();
    int rh[3], rw[3];
    #pragma unroll
    for(int k=0;k<3;k++){
        int r = h + 2*(k-1); if(r<0) r=-r; if(r>=Hh) r=2*(Hh-1)-r; rh[k]=r;
        int c = w + 2*(k-1); if(c<0) c=-c; if(c>=Ww) c=2*(Ww-1)-c; rw[k]=c;
    }
    float acc[16];
    #pragma unroll
    for(int o=0;o<16;o++) acc[o]=0.f;
    const float* xb = x + (size_t)n*Cc*HW;
    for(int c=0;c<Cc;c++){
        const float* xc = xb + (size_t)c*HW;
        float low=0.f, ctr=0.f;
        #pragma unroll
        for(int ki=0;ki<3;ki++){
            #pragma unroll
            for(int kj=0;kj<3;kj++){
                float v = xc[rh[ki]*Ww + rw[kj]];
                low += sf[c*9 + ki*3 + kj]*v;
                if(ki==1 && kj==1) ctr = v;
            }
        }
        high[((size_t)n*Cc + c)*HW + pix] = ctr - low;
        #pragma unroll
        for(int o=0;o<16;o++) acc[o] += sw[o*64+c]*low;
    }
    float a1 = *a1p;
    #pragma unroll
    for(int o=0;o<16;o++){
        float v = acc[o] + sb[o];
        v = v>=0.f ? v : a1*v;
        y1[((size_t)n*16 + o)*HW + pix] = v;
    }
}

// ---------------- kernels 4/5: depthwise3x3(dil) + conv1x1(16->16) + PReLU ----------------
template<int DILT>
__global__ void k_dw_c(const float* __restrict__ yin,
                       const float* __restrict__ dw, const float* __restrict__ db,
                       const float* __restrict__ wc, const float* __restrict__ bc,
                       const float* __restrict__ ap, float* __restrict__ yout){
    int bid = blockIdx.x;
    int n = bid/PIXBLK;
    int pix = (bid%PIXBLK)*256 + threadIdx.x;
    int h = pix/Ww, w = pix%Ww;
    __shared__ float sdw[16*9];
    __shared__ float swc[16*16];
    __shared__ float sdb[16], sbc[16];
    if(threadIdx.x<144) sdw[threadIdx.x] = dw[threadIdx.x];
    if(threadIdx.x>=144 && threadIdx.x<144+16){ sdb[threadIdx.x-144]=db[threadIdx.x-144]; }
    if(threadIdx.x>=160 && threadIdx.x<160+16){ sbc[threadIdx.x-160]=bc[threadIdx.x-160]; }
    for(int i=threadIdx.x;i<256;i+=256) swc[i]=wc[i];
    __syncthreads();
    float t16[16];
    const float* yb = yin + (size_t)n*16*HW;
    for(int c=0;c<16;c++){
        float s = 0.f;
        #pragma unroll
        for(int u=0;u<3;u++){
            int hh = h + DILT*(u-1);
            if(hh<0 || hh>=Hh) continue;
            #pragma unroll
            for(int v=0;v<3;v++){
                int wwi = w + DILT*(v-1);
                if(wwi<0 || wwi>=Ww) continue;
                s += yb[(size_t)c*HW + hh*Ww + wwi]*sdw[c*9+u*3+v];
            }
        }
        t16[c] = s + sdb[c];
    }
    float a = *ap;
    #pragma unroll
    for(int o=0;o<16;o++){
        float s = sbc[o];
        #pragma unroll
        for(int c=0;c<16;c++) s += swc[o*16+c]*t16[c];
        s = s>=0.f ? s : a*s;
        yout[((size_t)n*16 + o)*HW + pix] = s;
    }
}

// ---------------- kernel 6: dw3(dil3)+conv1x1+PReLU+conv1x1(16->64) -> enh_low ----------------
__global__ void k_dw3_final(const float* __restrict__ yin,
                            const float* __restrict__ dw, const float* __restrict__ db,
                            const float* __restrict__ w4, const float* __restrict__ b4,
                            const float* __restrict__ a4p,
                            const float* __restrict__ w5, const float* __restrict__ b5,
                            float* __restrict__ enh_low){
    int bid = blockIdx.x;
    int n = bid/PIXBLK;
    int pix = (bid%PIXBLK)*256 + threadIdx.x;
    int h = pix/Ww, w = pix%Ww;
    __shared__ float sdw[16*9];
    __shared__ float sw4[16*16];
    __shared__ float sw5[64*16];
    __shared__ float sdb[16], sb4[16], sb5[64];
    if(threadIdx.x<144) sdw[threadIdx.x]=dw[threadIdx.x];
    if(threadIdx.x<16){ sdb[threadIdx.x]=db[threadIdx.x]; sb4[threadIdx.x]=b4[threadIdx.x]; }
    if(threadIdx.x<64) sb5[threadIdx.x]=b5[threadIdx.x];
    for(int i=threadIdx.x;i<256;i+=256) sw4[i]=w4[i];
    for(int i=threadIdx.x;i<1024;i+=256) sw5[i]=w5[i];
    __syncthreads();
    float t16[16];
    const float* yb = yin + (size_t)n*16*HW;
    for(int c=0;c<16;c++){
        float s=0.f;
        #pragma unroll
        for(int u=0;u<3;u++){
            int hh = h + 3*(u-1);
            if(hh<0||hh>=Hh) continue;
            #pragma unroll
            for(int v=0;v<3;v++){
                int wwi = w + 3*(v-1);
                if(wwi<0||wwi>=Ww) continue;
                s += yb[(size_t)c*HW + hh*Ww + wwi]*sdw[c*9+u*3+v];
            }
        }
        t16[c] = s + sdb[c];
    }
    float a = *a4p;
    float y4[16];
    #pragma unroll
    for(int o=0;o<16;o++){
        float s = sb4[o];
        #pragma unroll
        for(int c=0;c<16;c++) s += sw4[o*16+c]*t16[c];
        y4[o] = s>=0.f ? s : a*s;
    }
    for(int o=0;o<64;o++){
        float s = sb5[o];
        #pragma unroll
        for(int c=0;c<16;c++) s += sw5[o*16+c]*y4[c];
        enh_low[((size_t)n*Cc + o)*HW + pix] = s;
    }
}

// ---------------- zero small stats ----------------
__global__ void k_zero(float* __restrict__ p, int nf){
    int i = blockIdx.x*64 + threadIdx.x;
    if(i<nf) p[i]=0.f;
}

// ---------------- kernel 7: high GN stats ----------------
__global__ void k_hstats(const float* __restrict__ high, float* __restrict__ st){
    int nc = blockIdx.x;                       // n*64+c
    const float* p = high + (size_t)nc*HW;
    float s=0.f, s2=0.f;
    for(int i=threadIdx.x;i<HW;i+=256){ float v=p[i]; s+=v; s2+=v*v; }
    for(int o=32;o>0;o>>=1){ s+=__shfl_down(s,o); s2+=__shfl_down(s2,o); }
    __shared__ float sm[8];
    int wid=threadIdx.x>>6, ln=threadIdx.x&63;
    if(ln==0){ sm[wid*2]=s; sm[wid*2+1]=s2; }
    __syncthreads();
    if(threadIdx.x==0){
        float a = sm[0]+sm[2]+sm[4]+sm[6];
        float b = sm[1]+sm[3]+sm[5]+sm[7];
        int g = nc>>4;                          // n*4 + c/16
        atomicAdd(&st[g*2],   a);
        atomicAdd(&st[g*2+1], b);
    }
}

// ---------------- kernel 8: high branch conv3x3 (GN+leaky on the fly) + residual ----------------
__global__ void k_conv3(const float* __restrict__ high, const float* __restrict__ st,
                        const float* __restrict__ gng, const float* __restrict__ gnb,
                        const float* __restrict__ hw, const float* __restrict__ hb,
                        float* __restrict__ enh_high){
    int bid = blockIdx.x;
    int og = bid & 3;
    int pc = (bid>>2) % PIXBLK;
    int n  = bid / (4*PIXBLK);
    int pix = pc*256 + threadIdx.x;
    int h = pix/Ww, w = pix%Ww;
    __shared__ float swt[16*64*9];              // 36864 B
    __shared__ float ssc[64], sbi[64];
    for(int i=threadIdx.x;i<16*64*9;i+=256) swt[i] = hw[(size_t)og*16*64*9 + i];
    if(threadIdx.x<64){
        int c = threadIdx.x;
        int g = n*4 + (c>>4);
        float cnt = 16.f*(float)HW;
        float m = st[g*2]/cnt;
        float var = st[g*2+1]/cnt - m*m;
        float sc = gng[c]*rsqrtf(var+1e-5f);
        ssc[c]=sc; sbi[c]=gnb[c]-m*sc;
    }
    __syncthreads();
    float acc[16];
    #pragma unroll
    for(int o=0;o<16;o++) acc[o]=0.f;
    const float* hbase = high + (size_t)n*Cc*HW;
    for(int ci=0;ci<64;ci++){
        const float* hp = hbase + (size_t)ci*HW;
        float sc=ssc[ci], bi=sbi[ci];
        float z[9];
        #pragma unroll
        for(int u=0;u<3;u++){
            int hh=h+u-1;
            #pragma unroll
            for(int v=0;v<3;v++){
                int wwi=w+v-1;
                float val=0.f;
                if(hh>=0&&hh<Hh&&wwi>=0&&wwi<Ww){
                    val = hp[hh*Ww+wwi]*sc+bi;
                    val = val>=0.f ? val : 0.01f*val;
                }
                z[u*3+v]=val;
            }
        }
        #pragma unroll
        for(int o=0;o<16;o++){
            const float* wo = &swt[(o*64+ci)*9];
            float s = acc[o];
            #pragma unroll
            for(int t=0;t<9;t++) s += z[t]*wo[t];
            acc[o]=s;
        }
    }
    #pragma unroll
    for(int o=0;o<16;o++){
        int oc = og*16+o;
        enh_high[((size_t)n*Cc+oc)*HW+pix] = acc[o] + hb[oc] + hbase[(size_t)oc*HW+pix];
    }
}

// ---------------- kernel 9: fusion conv1x1 128->128 + GN stats ----------------
__global__ void k_fu1(const float* __restrict__ enh_low, const float* __restrict__ enh_high,
                      const float* __restrict__ w, const float* __restrict__ b,
                      float* __restrict__ o1, float* __restrict__ st){
    int bid = blockIdx.x;
    int g = bid % 4;
    int r = bid / 4;
    int pc = r % PIXBLK;
    int n  = r / PIXBLK;
    int pix = pc*256 + threadIdx.x;
    __shared__ float sw[32*128];
    __shared__ float sb[32];
    for(int i=threadIdx.x;i<32*128;i+=256) sw[i] = w[(size_t)g*32*128 + i];
    if(threadIdx.x<32) sb[threadIdx.x] = b[g*32+threadIdx.x];
    __syncthreads();
    float acc[32];
    #pragma unroll
    for(int o=0;o<32;o++) acc[o]=sb[o];
    const float* el = enh_low  + (size_t)n*Cc*HW + pix;
    const float* eh = enh_high + (size_t)n*Cc*HW + pix;
    for(int c=0;c<64;c++){
        float v = el[(size_t)c*HW];
        #pragma unroll
        for(int o=0;o<32;o++) acc[o] += sw[o*128+c]*v;
    }
    for(int c=0;c<64;c++){
        float v = eh[(size_t)c*HW];
        #pragma unroll
        for(int o=0;o<32;o++) acc[o] += sw[o*128+64+c]*v;
    }
    float ls=0.f, ls2=0.f;
    #pragma unroll
    for(int o=0;o<32;o++){
        int oc = g*32+o;
        o1[((size_t)n*128+oc)*HW+pix] = acc[o];
        ls += acc[o]; ls2 += acc[o]*acc[o];
    }
    for(int o=32;o>0;o>>=1){ ls+=__shfl_down(ls,o); ls2+=__shfl_down(ls2,o); }
    __shared__ float sm[8];
    int wid=threadIdx.x>>6, ln=threadIdx.x&63;
    if(ln==0){ sm[wid*2]=ls; sm[wid*2+1]=ls2; }
    __syncthreads();
    if(threadIdx.x==0){
        float a = sm[0]+sm[2]+sm[4]+sm[6];
        float bb= sm[1]+sm[3]+sm[5]+sm[7];
        atomicAdd(&st[(n*4+g)*2],   a);
        atomicAdd(&st[(n*4+g)*2+1], bb);
    }
}

// ---------------- kernel 10: GN + GELU + conv1x1 128->64 -> out ----------------
__global__ void k_fu2(const float* __restrict__ o1, const float* __restrict__ st,
                      const float* __restrict__ gg, const float* __restrict__ gb,
                      const float* __restrict__ w2, const float* __restrict__ b2,
                      float* __restrict__ out){
    int bid = blockIdx.x;
    int n = bid/PIXBLK;
    int pc = bid%PIXBLK;
    int pix = pc*256 + threadIdx.x;
    __shared__ float sw[64*128];                // 32KB
    __shared__ float ssc[128], sbi[128], sb2[64];
    for(int i=threadIdx.x;i<64*128;i+=256) sw[i]=w2[i];
    if(threadIdx.x<128){
        int c=threadIdx.x;
        int g=n*4 + (c>>5);
        float cnt = 32.f*(float)HW;
        float m = st[g*2]/cnt;
        float var = st[g*2+1]/cnt - m*m;
        float sc = gg[c]*rsqrtf(var+1e-5f);
        ssc[c]=sc; sbi[c]=gb[c]-m*sc;
    }
    if(threadIdx.x<64) sb2[threadIdx.x]=b2[threadIdx.x];
    __syncthreads();
    float acc[64];
    #pragma unroll
    for(int o=0;o<64;o++) acc[o]=sb2[o];
    const float* ob = o1 + (size_t)n*128*HW + pix;
    for(int c=0;c<128;c++){
        float v = ob[(size_t)c*HW];
        v = v*ssc[c]+sbi[c];
        v = 0.5f*v*(1.f+erff(v*0.70710678118654752f));
        #pragma unroll
        for(int o=0;o<64;o++) acc[o] += sw[o*128+c]*v;
    }
    #pragma unroll
    for(int o=0;o<64;o++) out[((size_t)n*Cc+o)*HW+pix]=acc[o];
}

extern "C" void kernel_launch(void* const* d_in, const int* in_sizes, int n_in,
                              void* d_out, int out_size, void* d_ws, size_t ws_size,
                              hipStream_t stream) {
    const float* x        = (const float*)d_in[0];
    const float* w_filter = (const float*)d_in[1];
    const float* gnf_g    = (const float*)d_in[2];
    const float* gnf_b    = (const float*)d_in[3];
    const float* lb_w1    = (const float*)d_in[4];
    const float* lb_b1    = (const float*)d_in[5];
    const float* lb_a1    = (const float*)d_in[6];
    const float* lb_dw1   = (const float*)d_in[7];
    const float* lb_db1   = (const float*)d_in[8];
    const float* lb_w2    = (const float*)d_in[9];
    const float* lb_b2    = (const float*)d_in[10];
    const float* lb_a2    = (const float*)d_in[11];
    const float* lb_dw2   = (const float*)d_in[12];
    const float* lb_db2   = (const float*)d_in[13];
    const float* lb_w3    = (const float*)d_in[14];
    const float* lb_b3    = (const float*)d_in[15];
    const float* lb_a3    = (const float*)d_in[16];
    const float* lb_dw3   = (const float*)d_in[17];
    const float* lb_db3   = (const float*)d_in[18];
    const float* lb_w4    = (const float*)d_in[19];
    const float* lb_b4    = (const float*)d_in[20];
    const float* lb_a4    = (const float*)d_in[21];
    const float* lb_w5    = (const float*)d_in[22];
    const float* lb_b5    = (const float*)d_in[23];
    const float* hb_gn_g  = (const float*)d_in[24];
    const float* hb_gn_b  = (const float*)d_in[25];
    const float* hb_w     = (const float*)d_in[26];
    const float* hb_b     = (const float*)d_in[27];
    const float* fu_w1    = (const float*)d_in[28];
    const float* fu_b1    = (const float*)d_in[29];
    const float* fu_gn_g  = (const float*)d_in[30];
    const float* fu_gn_b  = (const float*)d_in[31];
    const float* fu_w2    = (const float*)d_in[32];
    const float* fu_b2    = (const float*)d_in[33];
    float* out = (float*)d_out;

    // ws layout (floats)
    const size_t PLANE = (size_t)Nn*Cc*HW;      // 9,437,184
    const size_t YSZ   = (size_t)Nn*16*HW;      // 2,359,296
    float* W = (float*)d_ws;
    float* enh_low  = W;                        // [0, P)
    float* enh_high = W + PLANE;                // [P, 2P)
    float* high     = W + 2*PLANE;              // [2P, 3P)  (dead after conv3)
    float* y1       = W + 3*PLANE;              // [3P, 3P+Y)
    float* y2       = W + 3*PLANE + YSZ;        // dead after dw chain
    float* o1       = W + 2*PLANE;              // aliases high/y1/y2: [2P, 4P)
    float* fp       = W + 4*PLANE;              // 256
    float* fsm      = W + 4*PLANE + 256;        // 2304
    float* st_hb    = W + 4*PLANE + 2560;       // 32
    float* st_o1    = W + 4*PLANE + 2592;       // 32

    k_zero<<<1, 64, 0, stream>>>(st_hb, 64);
    k_gap<<<Nn*Cc, 256, 0, stream>>>(x, fp);
    k_filter<<<Nn, 576, 0, stream>>>(fp, w_filter, gnf_g, gnf_b, fsm);
    k_lowhigh<<<Nn*PIXBLK, 256, 0, stream>>>(x, fsm, lb_w1, lb_b1, lb_a1, high, y1);
    k_dw_c<5><<<Nn*PIXBLK, 256, 0, stream>>>(y1, lb_dw1, lb_db1, lb_w2, lb_b2, lb_a2, y2);
    k_dw_c<1><<<Nn*PIXBLK, 256, 0, stream>>>(y2, lb_dw2, lb_db2, lb_w3, lb_b3, lb_a3, y1);
    k_dw3_final<<<Nn*PIXBLK, 256, 0, stream>>>(y1, lb_dw3, lb_db3, lb_w4, lb_b4, lb_a4,
                                               lb_w5, lb_b5, enh_low);
    k_hstats<<<Nn*Cc, 256, 0, stream>>>(high, st_hb);
    k_conv3<<<Nn*PIXBLK*4, 256, 0, stream>>>(high, st_hb, hb_gn_g, hb_gn_b, hb_w, hb_b, enh_high);
    k_fu1<<<Nn*PIXBLK*4, 256, 0, stream>>>(enh_low, enh_high, fu_w1, fu_b1, o1, st_o1);
    k_fu2<<<Nn*PIXBLK, 256, 0, stream>>>(o1, st_o1, fu_gn_g, fu_gn_b, fu_w2, fu_b2, out);
}

// Round 2
// 878.545 us; speedup vs baseline: 1.5017x; 1.5017x over previous
//
#include <hip/hip_runtime.h>
#include <hip/hip_bf16.h>
#include <math.h>

#define Nn 4
#define Cc 64
#define Hh 192
#define Ww 192
#define HW (Hh*Ww)          // 36864
#define PIXBLK 144          // HW/256

typedef __attribute__((ext_vector_type(4))) float f32x4;
typedef __attribute__((ext_vector_type(8))) short s16x8;

static __device__ __forceinline__ unsigned short f2bf(float v){
    __hip_bfloat16 b = __float2bfloat16(v);
    return *(unsigned short*)&b;
}

// ---------------- kernel 1: global average pool ----------------
__global__ void k_gap(const float* __restrict__ x, float* __restrict__ fp){
    int nc = blockIdx.x;                     // 0..255  (n*64+c)
    const float* p = x + (size_t)nc*HW;
    float s = 0.f;
    for(int i=threadIdx.x;i<HW;i+=256) s += p[i];
    for(int o=32;o>0;o>>=1) s += __shfl_down(s,o);
    __shared__ float sm[4];
    int wid = threadIdx.x>>6, ln = threadIdx.x&63;
    if(ln==0) sm[wid]=s;
    __syncthreads();
    if(threadIdx.x==0) fp[nc] = (sm[0]+sm[1]+sm[2]+sm[3]) / (float)HW;
}

// ---------------- kernel 2: dynamic filter (matvec + GN + softmax) ----------------
__global__ void k_filter(const float* __restrict__ fp, const float* __restrict__ wf,
                         const float* __restrict__ gg, const float* __restrict__ gb,
                         float* __restrict__ fsm){
    int n = blockIdx.x;
    __shared__ float sfp[64];
    __shared__ float sfw[576];
    __shared__ float gstat[8];
    int t = threadIdx.x;                       // 0..575
    if(t<64) sfp[t] = fp[n*64+t];
    __syncthreads();
    const float* wr = wf + (size_t)t*64;
    float acc = 0.f;
    #pragma unroll 8
    for(int k=0;k<64;k++) acc += sfp[k]*wr[k];
    sfw[t] = acc;
    __syncthreads();
    if(t<4){
        float s=0.f,s2=0.f;
        for(int i=0;i<144;i++){ float v=sfw[t*144+i]; s+=v; s2+=v*v; }
        float m = s/144.f;
        gstat[t*2]   = m;
        gstat[t*2+1] = s2/144.f - m*m;
    }
    __syncthreads();
    int g = t/144;
    float m = gstat[g*2], var = gstat[g*2+1];
    float z = (acc-m)*rsqrtf(var+1e-5f)*gg[t] + gb[t];
    sfw[t] = z;
    __syncthreads();
    if(t<64){
        float mx = -1e30f;
        for(int j=0;j<9;j++) mx = fmaxf(mx, sfw[t*9+j]);
        float e[9]; float se=0.f;
        for(int j=0;j<9;j++){ e[j]=expf(sfw[t*9+j]-mx); se+=e[j]; }
        float inv = 1.f/se;
        for(int j=0;j<9;j++) fsm[((size_t)n*64+t)*9+j] = e[j]*inv;
    }
}

// ---------------- kernel 3: low/high + conv1x1(64->16)+PReLU ----------------
__global__ void k_lowhigh(const float* __restrict__ x, const float* __restrict__ fsm,
                          const float* __restrict__ w1, const float* __restrict__ b1,
                          const float* __restrict__ a1p,
                          float* __restrict__ high, float* __restrict__ y1){
    int bid = blockIdx.x;
    int n = bid/PIXBLK;
    int pix = (bid%PIXBLK)*256 + threadIdx.x;
    int h = pix/Ww, w = pix%Ww;
    __shared__ float sf[64*9];
    __shared__ float sw[16*64];
    __shared__ float sb[16];
    for(int i=threadIdx.x;i<576;i+=256) sf[i] = fsm[(size_t)n*576+i];
    for(int i=threadIdx.x;i<1024;i+=256) sw[i] = w1[i];
    if(threadIdx.x<16) sb[threadIdx.x] = b1[threadIdx.x];
    __syncthreads();
    int rh[3], rw[3];
    #pragma unroll
    for(int k=0;k<3;k++){
        int r = h + 2*(k-1); if(r<0) r=-r; if(r>=Hh) r=2*(Hh-1)-r; rh[k]=r;
        int c = w + 2*(k-1); if(c<0) c=-c; if(c>=Ww) c=2*(Ww-1)-c; rw[k]=c;
    }
    float acc[16];
    #pragma unroll
    for(int o=0;o<16;o++) acc[o]=0.f;
    const float* xb = x + (size_t)n*Cc*HW;
    for(int c=0;c<Cc;c++){
        const float* xc = xb + (size_t)c*HW;
        float low=0.f, ctr=0.f;
        #pragma unroll
        for(int ki=0;ki<3;ki++){
            #pragma unroll
            for(int kj=0;kj<3;kj++){
                float v = xc[rh[ki]*Ww + rw[kj]];
                low += sf[c*9 + ki*3 + kj]*v;
                if(ki==1 && kj==1) ctr = v;
            }
        }
        high[((size_t)n*Cc + c)*HW + pix] = ctr - low;
        #pragma unroll
        for(int o=0;o<16;o++) acc[o] += sw[o*64+c]*low;
    }
    float a1 = *a1p;
    #pragma unroll
    for(int o=0;o<16;o++){
        float v = acc[o] + sb[o];
        v = v>=0.f ? v : a1*v;
        y1[((size_t)n*16 + o)*HW + pix] = v;
    }
}

// ---------------- kernels 4/5: depthwise3x3(dil) + conv1x1(16->16) + PReLU ----------------
template<int DILT>
__global__ void k_dw_c(const float* __restrict__ yin,
                       const float* __restrict__ dw, const float* __restrict__ db,
                       const float* __restrict__ wc, const float* __restrict__ bc,
                       const float* __restrict__ ap, float* __restrict__ yout){
    int bid = blockIdx.x;
    int n = bid/PIXBLK;
    int pix = (bid%PIXBLK)*256 + threadIdx.x;
    int h = pix/Ww, w = pix%Ww;
    __shared__ float sdw[16*9];
    __shared__ float swc[16*16];
    __shared__ float sdb[16], sbc[16];
    if(threadIdx.x<144) sdw[threadIdx.x] = dw[threadIdx.x];
    if(threadIdx.x>=144 && threadIdx.x<144+16){ sdb[threadIdx.x-144]=db[threadIdx.x-144]; }
    if(threadIdx.x>=160 && threadIdx.x<160+16){ sbc[threadIdx.x-160]=bc[threadIdx.x-160]; }
    for(int i=threadIdx.x;i<256;i+=256) swc[i]=wc[i];
    __syncthreads();
    float t16[16];
    const float* yb = yin + (size_t)n*16*HW;
    for(int c=0;c<16;c++){
        float s = 0.f;
        #pragma unroll
        for(int u=0;u<3;u++){
            int hh = h + DILT*(u-1);
            if(hh<0 || hh>=Hh) continue;
            #pragma unroll
            for(int v=0;v<3;v++){
                int wwi = w + DILT*(v-1);
                if(wwi<0 || wwi>=Ww) continue;
                s += yb[(size_t)c*HW + hh*Ww + wwi]*sdw[c*9+u*3+v];
            }
        }
        t16[c] = s + sdb[c];
    }
    float a = *ap;
    #pragma unroll
    for(int o=0;o<16;o++){
        float s = sbc[o];
        #pragma unroll
        for(int c=0;c<16;c++) s += swc[o*16+c]*t16[c];
        s = s>=0.f ? s : a*s;
        yout[((size_t)n*16 + o)*HW + pix] = s;
    }
}

// ---------------- kernel 6: dw3(dil3)+conv1x1+PReLU+conv1x1(16->64) -> enh_low ----------------
__global__ void k_dw3_final(const float* __restrict__ yin,
                            const float* __restrict__ dw, const float* __restrict__ db,
                            const float* __restrict__ w4, const float* __restrict__ b4,
                            const float* __restrict__ a4p,
                            const float* __restrict__ w5, const float* __restrict__ b5,
                            float* __restrict__ enh_low){
    int bid = blockIdx.x;
    int n = bid/PIXBLK;
    int pix = (bid%PIXBLK)*256 + threadIdx.x;
    int h = pix/Ww, w = pix%Ww;
    __shared__ float sdw[16*9];
    __shared__ float sw4[16*16];
    __shared__ float sw5[64*16];
    __shared__ float sdb[16], sb4[16], sb5[64];
    if(threadIdx.x<144) sdw[threadIdx.x]=dw[threadIdx.x];
    if(threadIdx.x<16){ sdb[threadIdx.x]=db[threadIdx.x]; sb4[threadIdx.x]=b4[threadIdx.x]; }
    if(threadIdx.x<64) sb5[threadIdx.x]=b5[threadIdx.x];
    for(int i=threadIdx.x;i<256;i+=256) sw4[i]=w4[i];
    for(int i=threadIdx.x;i<1024;i+=256) sw5[i]=w5[i];
    __syncthreads();
    float t16[16];
    const float* yb = yin + (size_t)n*16*HW;
    for(int c=0;c<16;c++){
        float s=0.f;
        #pragma unroll
        for(int u=0;u<3;u++){
            int hh = h + 3*(u-1);
            if(hh<0||hh>=Hh) continue;
            #pragma unroll
            for(int v=0;v<3;v++){
                int wwi = w + 3*(v-1);
                if(wwi<0||wwi>=Ww) continue;
                s += yb[(size_t)c*HW + hh*Ww + wwi]*sdw[c*9+u*3+v];
            }
        }
        t16[c] = s + sdb[c];
    }
    float a = *a4p;
    float y4[16];
    #pragma unroll
    for(int o=0;o<16;o++){
        float s = sb4[o];
        #pragma unroll
        for(int c=0;c<16;c++) s += sw4[o*16+c]*t16[c];
        y4[o] = s>=0.f ? s : a*s;
    }
    for(int o=0;o<64;o++){
        float s = sb5[o];
        #pragma unroll
        for(int c=0;c<16;c++) s += sw5[o*16+c]*y4[c];
        enh_low[((size_t)n*Cc + o)*HW + pix] = s;
    }
}

// ---------------- zero small stats ----------------
__global__ void k_zero(float* __restrict__ p, int nf){
    int i = blockIdx.x*64 + threadIdx.x;
    if(i<nf) p[i]=0.f;
}

// ---------------- kernel 7: high GN stats ----------------
__global__ void k_hstats(const float* __restrict__ high, float* __restrict__ st){
    int nc = blockIdx.x;                       // n*64+c
    const float* p = high + (size_t)nc*HW;
    float s=0.f, s2=0.f;
    for(int i=threadIdx.x;i<HW;i+=256){ float v=p[i]; s+=v; s2+=v*v; }
    for(int o=32;o>0;o>>=1){ s+=__shfl_down(s,o); s2+=__shfl_down(s2,o); }
    __shared__ float sm[8];
    int wid=threadIdx.x>>6, ln=threadIdx.x&63;
    if(ln==0){ sm[wid*2]=s; sm[wid*2+1]=s2; }
    __syncthreads();
    if(threadIdx.x==0){
        float a = sm[0]+sm[2]+sm[4]+sm[6];
        float b = sm[1]+sm[3]+sm[5]+sm[7];
        int g = nc>>4;                          // n*4 + c/16
        atomicAdd(&st[g*2],   a);
        atomicAdd(&st[g*2+1], b);
    }
}

// ---------------- weight prep for conv3 MFMA: transpose + bf16 + LDS-swizzle ----------------
// g_wt ushort layout: og*9216 + (t*16+o)*64 + (c ^ ((o&7)<<3))
__global__ void k_wprep(const float* __restrict__ hw, unsigned short* __restrict__ g_wt){
    int idx = blockIdx.x*256 + threadIdx.x;    // 0..36863
    int c = idx & 63;
    int o = (idx>>6) & 15;
    int t = (idx>>10) % 9;
    int og = idx / 9216;
    float v = hw[(size_t)(((og*16+o)*64)+c)*9 + t];
    g_wt[(size_t)og*9216 + (t*16+o)*64 + (c ^ ((o&7)<<3))] = f2bf(v);
}

// ---------------- kernel 8: conv3x3 64->64 via MFMA (GN+leaky fused in staging) ----------------
// grid: n(4) * og(4) * 144 tiles of 16x16 px; 256 threads (4 waves)
__global__ void __launch_bounds__(256,2)
k_conv3m(const float* __restrict__ high, const float* __restrict__ st,
         const float* __restrict__ gng, const float* __restrict__ gnb,
         const unsigned short* __restrict__ g_wt, const float* __restrict__ hb,
         float* __restrict__ enh_high){
    int bid = blockIdx.x;
    int tile = bid % 144;
    int og   = (bid/144) & 3;
    int n    = bid / 576;
    int tr0 = (tile/12)*16, tc0 = (tile%12)*16;
    __shared__ unsigned short z_lds[324*64];     // 41472 B, row=halo px (18x18), col=c, XOR-swizzled
    __shared__ unsigned short wt_lds[9*16*64];   // 18432 B, row=t*16+o, col=c, XOR-swizzled
    __shared__ float ssc[64], sbi[64];
    int tid = threadIdx.x;
    // weights: straight vector copy (already swizzled in global)
    {
        const uint4* src = (const uint4*)(g_wt + (size_t)og*9216);
        uint4* dst = (uint4*)wt_lds;
        for(int i=tid;i<1152;i+=256) dst[i]=src[i];
    }
    if(tid<64){
        int c=tid, g=n*4+(c>>4);
        float cnt=16.f*(float)HW;
        float m=st[g*2]/cnt, var=st[g*2+1]/cnt-m*m;
        float sc=gng[c]*rsqrtf(var+1e-5f);
        ssc[c]=sc; sbi[c]=gnb[c]-m*sc;
    }
    __syncthreads();
    // z staging: GN + leaky + bf16, zero outside image (conv zero-pad)
    const float* hbase = high + (size_t)n*Cc*HW;
    for(int e=tid;e<64*324;e+=256){
        int c = e/324, hpx = e - c*324;
        int hr = hpx/18, hc = hpx - hr*18;
        int gr = tr0+hr-1, gc = tc0+hc-1;
        float v = 0.f;
        if(gr>=0 && gr<Hh && gc>=0 && gc<Ww){
            v = hbase[(size_t)c*HW + gr*Ww + gc]*ssc[c] + sbi[c];
            v = v>=0.f ? v : 0.01f*v;
        }
        z_lds[hpx*64 + (c ^ ((hpx&7)<<3))] = f2bf(v);
    }
    __syncthreads();
    // MFMA: 9 taps x 2 k-blocks; per wave: M=16 oc, N=4 spatial rows x 16 cols
    int wv = tid>>6, ln = tid&63;
    int col = ln&15, kq = ln>>4;                 // col = px-in-row / oc-row-sel; kq = K-chunk
    f32x4 acc[4] = {{0.f,0.f,0.f,0.f},{0.f,0.f,0.f,0.f},{0.f,0.f,0.f,0.f},{0.f,0.f,0.f,0.f}};
    #pragma unroll
    for(int t=0;t<9;t++){
        int dr = t/3 - 1, dc = t%3 - 1;
        #pragma unroll
        for(int kb=0;kb<2;kb++){
            int k0 = kb*32 + kq*8;
            const s16x8 afr = *(const s16x8*)&wt_lds[(t*16+col)*64 + (k0 ^ ((col&7)<<3))];
            #pragma unroll
            for(int rf=0;rf<4;rf++){
                int r = wv*4 + rf;
                int hpx = (r+1+dr)*18 + (col+1+dc);
                const s16x8 bfr = *(const s16x8*)&z_lds[hpx*64 + (k0 ^ ((hpx&7)<<3))];
                acc[rf] = __builtin_amdgcn_mfma_f32_16x16x32_bf16(afr, bfr, acc[rf], 0, 0, 0);
            }
        }
    }
    // epilogue: D[o][px]: px-col = lane&15, oc = kq*4+reg ; + bias + residual
    #pragma unroll
    for(int rf=0;rf<4;rf++){
        int r = wv*4 + rf;
        int gpx = (tr0+r)*Ww + (tc0+col);
        #pragma unroll
        for(int reg=0;reg<4;reg++){
            int oc = og*16 + kq*4 + reg;
            enh_high[((size_t)n*Cc+oc)*HW + gpx] =
                acc[rf][reg] + hb[oc] + hbase[(size_t)oc*HW + gpx];
        }
    }
}

// ---------------- kernel 9: fusion conv1x1 128->128 + GN stats ----------------
__global__ void k_fu1(const float* __restrict__ enh_low, const float* __restrict__ enh_high,
                      const float* __restrict__ w, const float* __restrict__ b,
                      float* __restrict__ o1, float* __restrict__ st){
    int bid = blockIdx.x;
    int g = bid % 4;
    int r = bid / 4;
    int pc = r % PIXBLK;
    int n  = r / PIXBLK;
    int pix = pc*256 + threadIdx.x;
    __shared__ float sw[32*128];
    __shared__ float sb[32];
    for(int i=threadIdx.x;i<32*128;i+=256) sw[i] = w[(size_t)g*32*128 + i];
    if(threadIdx.x<32) sb[threadIdx.x] = b[g*32+threadIdx.x];
    __syncthreads();
    float acc[32];
    #pragma unroll
    for(int o=0;o<32;o++) acc[o]=sb[o];
    const float* el = enh_low  + (size_t)n*Cc*HW + pix;
    const float* eh = enh_high + (size_t)n*Cc*HW + pix;
    for(int c=0;c<64;c++){
        float v = el[(size_t)c*HW];
        #pragma unroll
        for(int o=0;o<32;o++) acc[o] += sw[o*128+c]*v;
    }
    for(int c=0;c<64;c++){
        float v = eh[(size_t)c*HW];
        #pragma unroll
        for(int o=0;o<32;o++) acc[o] += sw[o*128+64+c]*v;
    }
    float ls=0.f, ls2=0.f;
    #pragma unroll
    for(int o=0;o<32;o++){
        int oc = g*32+o;
        o1[((size_t)n*128+oc)*HW+pix] = acc[o];
        ls += acc[o]; ls2 += acc[o]*acc[o];
    }
    for(int o=32;o>0;o>>=1){ ls+=__shfl_down(ls,o); ls2+=__shfl_down(ls2,o); }
    __shared__ float sm[8];
    int wid=threadIdx.x>>6, ln=threadIdx.x&63;
    if(ln==0){ sm[wid*2]=ls; sm[wid*2+1]=ls2; }
    __syncthreads();
    if(threadIdx.x==0){
        float a = sm[0]+sm[2]+sm[4]+sm[6];
        float bb= sm[1]+sm[3]+sm[5]+sm[7];
        atomicAdd(&st[(n*4+g)*2],   a);
        atomicAdd(&st[(n*4+g)*2+1], bb);
    }
}

// ---------------- kernel 10: GN + GELU + conv1x1 128->64 -> out ----------------
__global__ void k_fu2(const float* __restrict__ o1, const float* __restrict__ st,
                      const float* __restrict__ gg, const float* __restrict__ gb,
                      const float* __restrict__ w2, const float* __restrict__ b2,
                      float* __restrict__ out){
    int bid = blockIdx.x;
    int n = bid/PIXBLK;
    int pc = bid%PIXBLK;
    int pix = pc*256 + threadIdx.x;
    __shared__ float sw[64*128];                // 32KB
    __shared__ float ssc[128], sbi[128], sb2[64];
    for(int i=threadIdx.x;i<64*128;i+=256) sw[i]=w2[i];
    if(threadIdx.x<128){
        int c=threadIdx.x;
        int g=n*4 + (c>>5);
        float cnt = 32.f*(float)HW;
        float m = st[g*2]/cnt;
        float var = st[g*2+1]/cnt - m*m;
        float sc = gg[c]*rsqrtf(var+1e-5f);
        ssc[c]=sc; sbi[c]=gb[c]-m*sc;
    }
    if(threadIdx.x<64) sb2[threadIdx.x]=b2[threadIdx.x];
    __syncthreads();
    float acc[64];
    #pragma unroll
    for(int o=0;o<64;o++) acc[o]=sb2[o];
    const float* ob = o1 + (size_t)n*128*HW + pix;
    for(int c=0;c<128;c++){
        float v = ob[(size_t)c*HW];
        v = v*ssc[c]+sbi[c];
        v = 0.5f*v*(1.f+erff(v*0.70710678118654752f));
        #pragma unroll
        for(int o=0;o<64;o++) acc[o] += sw[o*128+c]*v;
    }
    #pragma unroll
    for(int o=0;o<64;o++) out[((size_t)n*Cc+o)*HW+pix]=acc[o];
}

extern "C" void kernel_launch(void* const* d_in, const int* in_sizes, int n_in,
                              void* d_out, int out_size, void* d_ws, size_t ws_size,
                              hipStream_t stream) {
    const float* x        = (const float*)d_in[0];
    const float* w_filter = (const float*)d_in[1];
    const float* gnf_g    = (const float*)d_in[2];
    const float* gnf_b    = (const float*)d_in[3];
    const float* lb_w1    = (const float*)d_in[4];
    const float* lb_b1    = (const float*)d_in[5];
    const float* lb_a1    = (const float*)d_in[6];
    const float* lb_dw1   = (const float*)d_in[7];
    const float* lb_db1   = (const float*)d_in[8];
    const float* lb_w2    = (const float*)d_in[9];
    const float* lb_b2    = (const float*)d_in[10];
    const float* lb_a2    = (const float*)d_in[11];
    const float* lb_dw2   = (const float*)d_in[12];
    const float* lb_db2   = (const float*)d_in[13];
    const float* lb_w3    = (const float*)d_in[14];
    const float* lb_b3    = (const float*)d_in[15];
    const float* lb_a3    = (const float*)d_in[16];
    const float* lb_dw3   = (const float*)d_in[17];
    const float* lb_db3   = (const float*)d_in[18];
    const float* lb_w4    = (const float*)d_in[19];
    const float* lb_b4    = (const float*)d_in[20];
    const float* lb_a4    = (const float*)d_in[21];
    const float* lb_w5    = (const float*)d_in[22];
    const float* lb_b5    = (const float*)d_in[23];
    const float* hb_gn_g  = (const float*)d_in[24];
    const float* hb_gn_b  = (const float*)d_in[25];
    const float* hb_w     = (const float*)d_in[26];
    const float* hb_b     = (const float*)d_in[27];
    const float* fu_w1    = (const float*)d_in[28];
    const float* fu_b1    = (const float*)d_in[29];
    const float* fu_gn_g  = (const float*)d_in[30];
    const float* fu_gn_b  = (const float*)d_in[31];
    const float* fu_w2    = (const float*)d_in[32];
    const float* fu_b2    = (const float*)d_in[33];
    float* out = (float*)d_out;

    // ws layout (floats)
    const size_t PLANE = (size_t)Nn*Cc*HW;      // 9,437,184
    const size_t YSZ   = (size_t)Nn*16*HW;      // 2,359,296
    float* W = (float*)d_ws;
    float* enh_low  = W;                        // [0, P)
    float* enh_high = W + PLANE;                // [P, 2P)
    float* high     = W + 2*PLANE;              // [2P, 3P)  (dead after conv3m)
    float* y1       = W + 3*PLANE;              // [3P, 3P+Y)
    float* y2       = W + 3*PLANE + YSZ;        // dead after dw chain
    float* o1       = W + 2*PLANE;              // aliases high/y1/y2: [2P, 4P)
    float* fp       = W + 4*PLANE;              // 256
    float* fsm      = W + 4*PLANE + 256;        // 2304
    float* st_hb    = W + 4*PLANE + 2560;       // 32
    float* st_o1    = W + 4*PLANE + 2592;       // 32
    // g_wt reuses dead y1 region (wprep launched after dw chain, consumed by conv3m,
    // clobbered later by fu1's o1 write — which happens after conv3m)
    unsigned short* g_wt = (unsigned short*)y1;

    k_zero<<<1, 64, 0, stream>>>(st_hb, 64);
    k_gap<<<Nn*Cc, 256, 0, stream>>>(x, fp);
    k_filter<<<Nn, 576, 0, stream>>>(fp, w_filter, gnf_g, gnf_b, fsm);
    k_lowhigh<<<Nn*PIXBLK, 256, 0, stream>>>(x, fsm, lb_w1, lb_b1, lb_a1, high, y1);
    k_dw_c<5><<<Nn*PIXBLK, 256, 0, stream>>>(y1, lb_dw1, lb_db1, lb_w2, lb_b2, lb_a2, y2);
    k_dw_c<1><<<Nn*PIXBLK, 256, 0, stream>>>(y2, lb_dw2, lb_db2, lb_w3, lb_b3, lb_a3, y1);
    k_dw3_final<<<Nn*PIXBLK, 256, 0, stream>>>(y1, lb_dw3, lb_db3, lb_w4, lb_b4, lb_a4,
                                               lb_w5, lb_b5, enh_low);
    k_wprep<<<144, 256, 0, stream>>>(hb_w, g_wt);
    k_hstats<<<Nn*Cc, 256, 0, stream>>>(high, st_hb);
    k_conv3m<<<Nn*4*144, 256, 0, stream>>>(high, st_hb, hb_gn_g, hb_gn_b, g_wt, hb_b, enh_high);
    k_fu1<<<Nn*PIXBLK*4, 256, 0, stream>>>(enh_low, enh_high, fu_w1, fu_b1, o1, st_o1);
    k_fu2<<<Nn*PIXBLK, 256, 0, stream>>>(o1, st_o1, fu_gn_g, fu_gn_b, fu_w2, fu_b2, out);
}

// Round 3
// 834.968 us; speedup vs baseline: 1.5800x; 1.0522x over previous
//
#include <hip/hip_runtime.h>
#include <hip/hip_bf16.h>
#include <math.h>

#define Nn 4
#define Cc 64
#define Hh 192
#define Ww 192
#define HW (Hh*Ww)          // 36864
#define PIXBLK 144          // HW/256

typedef __attribute__((ext_vector_type(4))) float f32x4;
typedef __attribute__((ext_vector_type(8))) short s16x8;

struct __align__(8) US4 { unsigned short x,y,z,w; };

static __device__ __forceinline__ unsigned short f2bf(float v){
    __hip_bfloat16 b = __float2bfloat16(v);
    return *(unsigned short*)&b;
}
static __device__ __forceinline__ float bf2f(unsigned int u){
    return __uint_as_float(u<<16);
}

// ---------------- kernel 1: global average pool ----------------
__global__ void k_gap(const float* __restrict__ x, float* __restrict__ fp){
    int nc = blockIdx.x;                     // 0..255  (n*64+c)
    const float* p = x + (size_t)nc*HW;
    float s = 0.f;
    for(int i=threadIdx.x;i<HW;i+=256) s += p[i];
    for(int o=32;o>0;o>>=1) s += __shfl_down(s,o);
    __shared__ float sm[4];
    int wid = threadIdx.x>>6, ln = threadIdx.x&63;
    if(ln==0) sm[wid]=s;
    __syncthreads();
    if(threadIdx.x==0) fp[nc] = (sm[0]+sm[1]+sm[2]+sm[3]) / (float)HW;
}

// ---------------- kernel 2: dynamic filter (matvec + GN + softmax) ----------------
__global__ void k_filter(const float* __restrict__ fp, const float* __restrict__ wf,
                         const float* __restrict__ gg, const float* __restrict__ gb,
                         float* __restrict__ fsm){
    int n = blockIdx.x;
    __shared__ float sfp[64];
    __shared__ float sfw[576];
    __shared__ float gstat[8];
    int t = threadIdx.x;                       // 0..575
    if(t<64) sfp[t] = fp[n*64+t];
    __syncthreads();
    const float* wr = wf + (size_t)t*64;
    float acc = 0.f;
    #pragma unroll 8
    for(int k=0;k<64;k++) acc += sfp[k]*wr[k];
    sfw[t] = acc;
    __syncthreads();
    if(t<4){
        float s=0.f,s2=0.f;
        for(int i=0;i<144;i++){ float v=sfw[t*144+i]; s+=v; s2+=v*v; }
        float m = s/144.f;
        gstat[t*2]   = m;
        gstat[t*2+1] = s2/144.f - m*m;
    }
    __syncthreads();
    int g = t/144;
    float m = gstat[g*2], var = gstat[g*2+1];
    float z = (acc-m)*rsqrtf(var+1e-5f)*gg[t] + gb[t];
    sfw[t] = z;
    __syncthreads();
    if(t<64){
        float mx = -1e30f;
        for(int j=0;j<9;j++) mx = fmaxf(mx, sfw[t*9+j]);
        float e[9]; float se=0.f;
        for(int j=0;j<9;j++){ e[j]=expf(sfw[t*9+j]-mx); se+=e[j]; }
        float inv = 1.f/se;
        for(int j=0;j<9;j++) fsm[((size_t)n*64+t)*9+j] = e[j]*inv;
    }
}

// ---------------- kernel 3: low/high + conv1x1(64->16)+PReLU ----------------
__global__ void k_lowhigh(const float* __restrict__ x, const float* __restrict__ fsm,
                          const float* __restrict__ w1, const float* __restrict__ b1,
                          const float* __restrict__ a1p,
                          float* __restrict__ high, float* __restrict__ y1){
    int bid = blockIdx.x;
    int n = bid/PIXBLK;
    int pix = (bid%PIXBLK)*256 + threadIdx.x;
    int h = pix/Ww, w = pix%Ww;
    __shared__ float sf[64*9];
    __shared__ float sw[16*64];
    __shared__ float sb[16];
    for(int i=threadIdx.x;i<576;i+=256) sf[i] = fsm[(size_t)n*576+i];
    for(int i=threadIdx.x;i<1024;i+=256) sw[i] = w1[i];
    if(threadIdx.x<16) sb[threadIdx.x] = b1[threadIdx.x];
    __syncthreads();
    int rh[3], rw[3];
    #pragma unroll
    for(int k=0;k<3;k++){
        int r = h + 2*(k-1); if(r<0) r=-r; if(r>=Hh) r=2*(Hh-1)-r; rh[k]=r;
        int c = w + 2*(k-1); if(c<0) c=-c; if(c>=Ww) c=2*(Ww-1)-c; rw[k]=c;
    }
    float acc[16];
    #pragma unroll
    for(int o=0;o<16;o++) acc[o]=0.f;
    const float* xb = x + (size_t)n*Cc*HW;
    for(int c=0;c<Cc;c++){
        const float* xc = xb + (size_t)c*HW;
        float low=0.f, ctr=0.f;
        #pragma unroll
        for(int ki=0;ki<3;ki++){
            #pragma unroll
            for(int kj=0;kj<3;kj++){
                float v = xc[rh[ki]*Ww + rw[kj]];
                low += sf[c*9 + ki*3 + kj]*v;
                if(ki==1 && kj==1) ctr = v;
            }
        }
        high[((size_t)n*Cc + c)*HW + pix] = ctr - low;
        #pragma unroll
        for(int o=0;o<16;o++) acc[o] += sw[o*64+c]*low;
    }
    float a1 = *a1p;
    #pragma unroll
    for(int o=0;o<16;o++){
        float v = acc[o] + sb[o];
        v = v>=0.f ? v : a1*v;
        y1[((size_t)n*16 + o)*HW + pix] = v;
    }
}

// ---------------- kernels 4/5: depthwise3x3(dil) + conv1x1(16->16) + PReLU ----------------
template<int DILT>
__global__ void k_dw_c(const float* __restrict__ yin,
                       const float* __restrict__ dw, const float* __restrict__ db,
                       const float* __restrict__ wc, const float* __restrict__ bc,
                       const float* __restrict__ ap, float* __restrict__ yout){
    int bid = blockIdx.x;
    int n = bid/PIXBLK;
    int pix = (bid%PIXBLK)*256 + threadIdx.x;
    int h = pix/Ww, w = pix%Ww;
    __shared__ float sdw[16*9];
    __shared__ float swc[16*16];
    __shared__ float sdb[16], sbc[16];
    if(threadIdx.x<144) sdw[threadIdx.x] = dw[threadIdx.x];
    if(threadIdx.x>=144 && threadIdx.x<144+16){ sdb[threadIdx.x-144]=db[threadIdx.x-144]; }
    if(threadIdx.x>=160 && threadIdx.x<160+16){ sbc[threadIdx.x-160]=bc[threadIdx.x-160]; }
    for(int i=threadIdx.x;i<256;i+=256) swc[i]=wc[i];
    __syncthreads();
    float t16[16];
    const float* yb = yin + (size_t)n*16*HW;
    for(int c=0;c<16;c++){
        float s = 0.f;
        #pragma unroll
        for(int u=0;u<3;u++){
            int hh = h + DILT*(u-1);
            if(hh<0 || hh>=Hh) continue;
            #pragma unroll
            for(int v=0;v<3;v++){
                int wwi = w + DILT*(v-1);
                if(wwi<0 || wwi>=Ww) continue;
                s += yb[(size_t)c*HW + hh*Ww + wwi]*sdw[c*9+u*3+v];
            }
        }
        t16[c] = s + sdb[c];
    }
    float a = *ap;
    #pragma unroll
    for(int o=0;o<16;o++){
        float s = sbc[o];
        #pragma unroll
        for(int c=0;c<16;c++) s += swc[o*16+c]*t16[c];
        s = s>=0.f ? s : a*s;
        yout[((size_t)n*16 + o)*HW + pix] = s;
    }
}

// ---------------- kernel 6: dw3(dil3)+conv1x1+PReLU+conv1x1(16->64) -> enh_low(bf16,pix-major) ----------------
__global__ void k_dw3_final(const float* __restrict__ yin,
                            const float* __restrict__ dw, const float* __restrict__ db,
                            const float* __restrict__ w4, const float* __restrict__ b4,
                            const float* __restrict__ a4p,
                            const float* __restrict__ w5, const float* __restrict__ b5,
                            unsigned short* __restrict__ enh_low){
    int bid = blockIdx.x;
    int n = bid/PIXBLK;
    int pix = (bid%PIXBLK)*256 + threadIdx.x;
    int h = pix/Ww, w = pix%Ww;
    __shared__ float sdw[16*9];
    __shared__ float sw4[16*16];
    __shared__ float sw5[64*16];
    __shared__ float sdb[16], sb4[16], sb5[64];
    if(threadIdx.x<144) sdw[threadIdx.x]=dw[threadIdx.x];
    if(threadIdx.x<16){ sdb[threadIdx.x]=db[threadIdx.x]; sb4[threadIdx.x]=b4[threadIdx.x]; }
    if(threadIdx.x<64) sb5[threadIdx.x]=b5[threadIdx.x];
    for(int i=threadIdx.x;i<256;i+=256) sw4[i]=w4[i];
    for(int i=threadIdx.x;i<1024;i+=256) sw5[i]=w5[i];
    __syncthreads();
    float t16[16];
    const float* yb = yin + (size_t)n*16*HW;
    for(int c=0;c<16;c++){
        float s=0.f;
        #pragma unroll
        for(int u=0;u<3;u++){
            int hh = h + 3*(u-1);
            if(hh<0||hh>=Hh) continue;
            #pragma unroll
            for(int v=0;v<3;v++){
                int wwi = w + 3*(v-1);
                if(wwi<0||wwi>=Ww) continue;
                s += yb[(size_t)c*HW + hh*Ww + wwi]*sdw[c*9+u*3+v];
            }
        }
        t16[c] = s + sdb[c];
    }
    float a = *a4p;
    float y4[16];
    #pragma unroll
    for(int o=0;o<16;o++){
        float s = sb4[o];
        #pragma unroll
        for(int c=0;c<16;c++) s += sw4[o*16+c]*t16[c];
        y4[o] = s>=0.f ? s : a*s;
    }
    unsigned short* dst = enh_low + ((size_t)n*HW + pix)*64;
    #pragma unroll
    for(int ob=0;ob<64;ob+=4){
        unsigned short tmp[4];
        #pragma unroll
        for(int j=0;j<4;j++){
            int o=ob+j;
            float s = sb5[o];
            #pragma unroll
            for(int c=0;c<16;c++) s += sw5[o*16+c]*y4[c];
            tmp[j]=f2bf(s);
        }
        US4 pk; pk.x=tmp[0]; pk.y=tmp[1]; pk.z=tmp[2]; pk.w=tmp[3];
        *(US4*)&dst[ob] = pk;
    }
}

// ---------------- zero small stats ----------------
__global__ void k_zero(float* __restrict__ p, int nf){
    int i = blockIdx.x*64 + threadIdx.x;
    if(i<nf) p[i]=0.f;
}

// ---------------- kernel 7: high GN stats ----------------
__global__ void k_hstats(const float* __restrict__ high, float* __restrict__ st){
    int nc = blockIdx.x;                       // n*64+c
    const float* p = high + (size_t)nc*HW;
    float s=0.f, s2=0.f;
    for(int i=threadIdx.x;i<HW;i+=256){ float v=p[i]; s+=v; s2+=v*v; }
    for(int o=32;o>0;o>>=1){ s+=__shfl_down(s,o); s2+=__shfl_down(s2,o); }
    __shared__ float sm[8];
    int wid=threadIdx.x>>6, ln=threadIdx.x&63;
    if(ln==0){ sm[wid*2]=s; sm[wid*2+1]=s2; }
    __syncthreads();
    if(threadIdx.x==0){
        float a = sm[0]+sm[2]+sm[4]+sm[6];
        float b = sm[1]+sm[3]+sm[5]+sm[7];
        int g = nc>>4;                          // n*4 + c/16
        atomicAdd(&st[g*2],   a);
        atomicAdd(&st[g*2+1], b);
    }
}

// ---------------- weight prep: conv3 + fu1 + fu2 (bf16 + swizzle) ----------------
// conv3: g_wt[og*9216 + (t*16+o)*64 + (c ^ ((o&7)<<3))]
// fu1:   g_wfu1[o*128 + (c ^ ((o&15)<<3))]   (o<128, c<128)
// fu2:   g_wfu2[o*128 + (c ^ ((o&15)<<3))]   (o<64,  c<128)
__global__ void k_wprep2(const float* __restrict__ hw, const float* __restrict__ fw1,
                         const float* __restrict__ fw2,
                         unsigned short* __restrict__ g_wt,
                         unsigned short* __restrict__ g_wfu1,
                         unsigned short* __restrict__ g_wfu2){
    int idx = blockIdx.x*256 + threadIdx.x;    // 0..61439
    if(idx<36864){
        int c = idx & 63;
        int o = (idx>>6) & 15;
        int t = (idx>>10) % 9;
        int og = idx / 9216;
        float v = hw[(size_t)(((og*16+o)*64)+c)*9 + t];
        g_wt[(size_t)og*9216 + (t*16+o)*64 + (c ^ ((o&7)<<3))] = f2bf(v);
    } else if(idx<53248){
        int i = idx-36864;
        int o = i>>7, c = i&127;
        g_wfu1[o*128 + (c ^ ((o&15)<<3))] = f2bf(fw1[i]);
    } else {
        int i = idx-53248;
        int o = i>>7, c = i&127;
        g_wfu2[o*128 + (c ^ ((o&15)<<3))] = f2bf(fw2[i]);
    }
}

// ---------------- kernel 8: conv3x3 64->64 via MFMA -> enh_high(bf16,pix-major) ----------------
__global__ void __launch_bounds__(256,2)
k_conv3m(const float* __restrict__ high, const float* __restrict__ st,
         const float* __restrict__ gng, const float* __restrict__ gnb,
         const unsigned short* __restrict__ g_wt, const float* __restrict__ hb,
         unsigned short* __restrict__ enh_high){
    int bid = blockIdx.x;
    int tile = bid % 144;
    int og   = (bid/144) & 3;
    int n    = bid / 576;
    int tr0 = (tile/12)*16, tc0 = (tile%12)*16;
    __shared__ __align__(16) unsigned short z_lds[324*64];     // 41472 B
    __shared__ __align__(16) unsigned short wt_lds[9*16*64];   // 18432 B
    __shared__ float ssc[64], sbi[64];
    int tid = threadIdx.x;
    {
        const uint4* src = (const uint4*)(g_wt + (size_t)og*9216);
        uint4* dst = (uint4*)wt_lds;
        for(int i=tid;i<1152;i+=256) dst[i]=src[i];
    }
    if(tid<64){
        int c=tid, g=n*4+(c>>4);
        float cnt=16.f*(float)HW;
        float m=st[g*2]/cnt, var=st[g*2+1]/cnt-m*m;
        float sc=gng[c]*rsqrtf(var+1e-5f);
        ssc[c]=sc; sbi[c]=gnb[c]-m*sc;
    }
    __syncthreads();
    const float* hbase = high + (size_t)n*Cc*HW;
    for(int e=tid;e<64*324;e+=256){
        int c = e/324, hpx = e - c*324;
        int hr = hpx/18, hc = hpx - hr*18;
        int gr = tr0+hr-1, gc = tc0+hc-1;
        float v = 0.f;
        if(gr>=0 && gr<Hh && gc>=0 && gc<Ww){
            v = hbase[(size_t)c*HW + gr*Ww + gc]*ssc[c] + sbi[c];
            v = v>=0.f ? v : 0.01f*v;
        }
        z_lds[hpx*64 + (c ^ ((hpx&7)<<3))] = f2bf(v);
    }
    __syncthreads();
    int wv = tid>>6, ln = tid&63;
    int col = ln&15, kq = ln>>4;
    f32x4 acc[4] = {{0.f,0.f,0.f,0.f},{0.f,0.f,0.f,0.f},{0.f,0.f,0.f,0.f},{0.f,0.f,0.f,0.f}};
    #pragma unroll
    for(int t=0;t<9;t++){
        int dr = t/3 - 1, dc = t%3 - 1;
        #pragma unroll
        for(int kb=0;kb<2;kb++){
            int k0 = kb*32 + kq*8;
            const s16x8 afr = *(const s16x8*)&wt_lds[(t*16+col)*64 + (k0 ^ ((col&7)<<3))];
            #pragma unroll
            for(int rf=0;rf<4;rf++){
                int r = wv*4 + rf;
                int hpx = (r+1+dr)*18 + (col+1+dc);
                const s16x8 bfr = *(const s16x8*)&z_lds[hpx*64 + (k0 ^ ((hpx&7)<<3))];
                acc[rf] = __builtin_amdgcn_mfma_f32_16x16x32_bf16(afr, bfr, acc[rf], 0, 0, 0);
            }
        }
    }
    #pragma unroll
    for(int rf=0;rf<4;rf++){
        int r = wv*4 + rf;
        int gpx = (tr0+r)*Ww + (tc0+col);
        unsigned short tmp[4];
        #pragma unroll
        for(int reg=0;reg<4;reg++){
            int oc = og*16 + kq*4 + reg;
            tmp[reg] = f2bf(acc[rf][reg] + hb[oc] + hbase[(size_t)oc*HW + gpx]);
        }
        US4 pk; pk.x=tmp[0]; pk.y=tmp[1]; pk.z=tmp[2]; pk.w=tmp[3];
        *(US4*)&enh_high[((size_t)n*HW + gpx)*64 + og*16 + kq*4] = pk;
    }
}

// ---------------- kernel 9: fusion conv1x1 128->128 via MFMA + GN stats -> o1(bf16) ----------------
__global__ void __launch_bounds__(256,2)
k_fu1m(const unsigned short* __restrict__ el, const unsigned short* __restrict__ eh,
       const unsigned short* __restrict__ wA, const float* __restrict__ b,
       unsigned short* __restrict__ o1, float* __restrict__ st){
    int bid = blockIdx.x;
    int n = bid/288, pt = bid%288;
    int px0 = pt*128;
    __shared__ __align__(16) unsigned short sA[128*128];   // 32 KB
    __shared__ __align__(16) unsigned short sB[128*128];   // 32 KB
    __shared__ float sb[128];
    int tid = threadIdx.x;
    {
        const uint4* s=(const uint4*)wA; uint4* d=(uint4*)sA;
        for(int i=tid;i<2048;i+=256) d[i]=s[i];
    }
    if(tid<128) sb[tid]=b[tid];
    {
        const uint4* se=(const uint4*)(el + ((size_t)n*HW+px0)*64);
        const uint4* sh=(const uint4*)(eh + ((size_t)n*HW+px0)*64);
        for(int i=tid;i<2048;i+=256){
            int px=i>>4, q=i&15;
            uint4 v = (q<8)? se[px*8+q] : sh[px*8+(q-8)];
            int c0 = q*8;
            *(uint4*)&sB[px*128 + (c0 ^ ((px&15)<<3))] = v;
        }
    }
    __syncthreads();
    int wv=tid>>6, ln=tid&63;
    int wm=wv>>1, wn=wv&1;
    int col=ln&15, kq=ln>>4;
    f32x4 acc[4][4];
    #pragma unroll
    for(int m=0;m<4;m++)
        #pragma unroll
        for(int nf=0;nf<4;nf++) acc[m][nf]=(f32x4){0.f,0.f,0.f,0.f};
    #pragma unroll
    for(int kb=0;kb<4;kb++){
        int k0 = kb*32 + kq*8;
        s16x8 a[4], bf[4];
        #pragma unroll
        for(int m=0;m<4;m++)
            a[m] = *(const s16x8*)&sA[(wm*64+m*16+col)*128 + (k0 ^ (col<<3))];
        #pragma unroll
        for(int nf=0;nf<4;nf++)
            bf[nf] = *(const s16x8*)&sB[(wn*64+nf*16+col)*128 + (k0 ^ (col<<3))];
        #pragma unroll
        for(int m=0;m<4;m++)
            #pragma unroll
            for(int nf=0;nf<4;nf++)
                acc[m][nf] = __builtin_amdgcn_mfma_f32_16x16x32_bf16(a[m], bf[nf], acc[m][nf], 0,0,0);
    }
    // epilogue: bias + stats + bf16 store (o1 layout [n][px][128])
    float sg0=0.f,sq0=0.f,sg1=0.f,sq1=0.f;
    #pragma unroll
    for(int m=0;m<4;m++){
        int oc0 = wm*64 + m*16 + kq*4;
        #pragma unroll
        for(int nf=0;nf<4;nf++){
            int px = wn*64 + nf*16 + col;
            unsigned short tmp[4];
            #pragma unroll
            for(int reg=0;reg<4;reg++){
                float v = acc[m][nf][reg] + sb[oc0+reg];
                if(m<2){ sg0+=v; sq0+=v*v; } else { sg1+=v; sq1+=v*v; }
                tmp[reg]=f2bf(v);
            }
            US4 pk; pk.x=tmp[0]; pk.y=tmp[1]; pk.z=tmp[2]; pk.w=tmp[3];
            *(US4*)&o1[((size_t)n*HW + px0 + px)*128 + oc0] = pk;
        }
    }
    #pragma unroll
    for(int o=32;o>0;o>>=1){
        sg0+=__shfl_down(sg0,o); sq0+=__shfl_down(sq0,o);
        sg1+=__shfl_down(sg1,o); sq1+=__shfl_down(sq1,o);
    }
    if(ln==0){
        int g0 = n*4 + wm*2, g1 = g0+1;
        atomicAdd(&st[g0*2],   sg0); atomicAdd(&st[g0*2+1], sq0);
        atomicAdd(&st[g1*2],   sg1); atomicAdd(&st[g1*2+1], sq1);
    }
}

// ---------------- kernel 10: GN + GELU + conv1x1 128->64 via MFMA -> out(f32) ----------------
__global__ void __launch_bounds__(256,2)
k_fu2m(const unsigned short* __restrict__ o1, const float* __restrict__ st,
       const float* __restrict__ gg, const float* __restrict__ gb,
       const unsigned short* __restrict__ wA, const float* __restrict__ b2,
       float* __restrict__ out){
    int bid = blockIdx.x;
    int n = bid/288, pt = bid%288;
    int px0 = pt*128;
    __shared__ __align__(16) unsigned short sA[64*128];    // 16 KB
    __shared__ __align__(16) unsigned short sB[128*128];   // 32 KB
    __shared__ float ssc[128], sbi[128], sb2[64];
    int tid = threadIdx.x;
    {
        const uint4* s=(const uint4*)wA; uint4* d=(uint4*)sA;
        for(int i=tid;i<1024;i+=256) d[i]=s[i];
    }
    if(tid<128){
        int c=tid, g=n*4+(c>>5);
        float cnt = 32.f*(float)HW;
        float m = st[g*2]/cnt;
        float var = st[g*2+1]/cnt - m*m;
        float sc = gg[c]*rsqrtf(var+1e-5f);
        ssc[c]=sc; sbi[c]=gb[c]-m*sc;
    }
    if(tid<64) sb2[tid]=b2[tid];
    __syncthreads();
    {
        const uint4* so=(const uint4*)(o1 + ((size_t)n*HW+px0)*128);
        for(int i=tid;i<2048;i+=256){
            int px=i>>4, q=i&15;
            int c0 = q*8;
            uint4 v = so[px*16+q];
            unsigned int vals[4] = {v.x,v.y,v.z,v.w};
            #pragma unroll
            for(int j=0;j<4;j++){
                int c = c0 + 2*j;
                float f0 = bf2f(vals[j]&0xffffu)*ssc[c]   + sbi[c];
                float f1 = bf2f(vals[j]>>16)   *ssc[c+1] + sbi[c+1];
                f0 = 0.5f*f0*(1.f+erff(f0*0.70710678118654752f));
                f1 = 0.5f*f1*(1.f+erff(f1*0.70710678118654752f));
                vals[j] = (unsigned int)f2bf(f0) | ((unsigned int)f2bf(f1)<<16);
            }
            uint4 w; w.x=vals[0]; w.y=vals[1]; w.z=vals[2]; w.w=vals[3];
            *(uint4*)&sB[px*128 + (c0 ^ ((px&15)<<3))] = w;
        }
    }
    __syncthreads();
    int wv=tid>>6, ln=tid&63;
    int col=ln&15, kq=ln>>4;
    f32x4 acc[4][2];
    #pragma unroll
    for(int m=0;m<4;m++){ acc[m][0]=(f32x4){0,0,0,0}; acc[m][1]=(f32x4){0,0,0,0}; }
    #pragma unroll
    for(int kb=0;kb<4;kb++){
        int k0 = kb*32 + kq*8;
        s16x8 a[4], bf[2];
        #pragma unroll
        for(int m=0;m<4;m++)
            a[m] = *(const s16x8*)&sA[(m*16+col)*128 + (k0 ^ (col<<3))];
        #pragma unroll
        for(int nf=0;nf<2;nf++)
            bf[nf] = *(const s16x8*)&sB[(wv*32+nf*16+col)*128 + (k0 ^ (col<<3))];
        #pragma unroll
        for(int m=0;m<4;m++)
            #pragma unroll
            for(int nf=0;nf<2;nf++)
                acc[m][nf] = __builtin_amdgcn_mfma_f32_16x16x32_bf16(a[m], bf[nf], acc[m][nf], 0,0,0);
    }
    #pragma unroll
    for(int m=0;m<4;m++){
        int oc0 = m*16 + kq*4;
        #pragma unroll
        for(int nf=0;nf<2;nf++){
            int px = px0 + wv*32 + nf*16 + col;
            #pragma unroll
            for(int reg=0;reg<4;reg++){
                int oc = oc0+reg;
                out[((size_t)n*64+oc)*HW + px] = acc[m][nf][reg] + sb2[oc];
            }
        }
    }
}

extern "C" void kernel_launch(void* const* d_in, const int* in_sizes, int n_in,
                              void* d_out, int out_size, void* d_ws, size_t ws_size,
                              hipStream_t stream) {
    const float* x        = (const float*)d_in[0];
    const float* w_filter = (const float*)d_in[1];
    const float* gnf_g    = (const float*)d_in[2];
    const float* gnf_b    = (const float*)d_in[3];
    const float* lb_w1    = (const float*)d_in[4];
    const float* lb_b1    = (const float*)d_in[5];
    const float* lb_a1    = (const float*)d_in[6];
    const float* lb_dw1   = (const float*)d_in[7];
    const float* lb_db1   = (const float*)d_in[8];
    const float* lb_w2    = (const float*)d_in[9];
    const float* lb_b2    = (const float*)d_in[10];
    const float* lb_a2    = (const float*)d_in[11];
    const float* lb_dw2   = (const float*)d_in[12];
    const float* lb_db2   = (const float*)d_in[13];
    const float* lb_w3    = (const float*)d_in[14];
    const float* lb_b3    = (const float*)d_in[15];
    const float* lb_a3    = (const float*)d_in[16];
    const float* lb_dw3   = (const float*)d_in[17];
    const float* lb_db3   = (const float*)d_in[18];
    const float* lb_w4    = (const float*)d_in[19];
    const float* lb_b4    = (const float*)d_in[20];
    const float* lb_a4    = (const float*)d_in[21];
    const float* lb_w5    = (const float*)d_in[22];
    const float* lb_b5    = (const float*)d_in[23];
    const float* hb_gn_g  = (const float*)d_in[24];
    const float* hb_gn_b  = (const float*)d_in[25];
    const float* hb_w     = (const float*)d_in[26];
    const float* hb_b     = (const float*)d_in[27];
    const float* fu_w1    = (const float*)d_in[28];
    const float* fu_b1    = (const float*)d_in[29];
    const float* fu_gn_g  = (const float*)d_in[30];
    const float* fu_gn_b  = (const float*)d_in[31];
    const float* fu_w2    = (const float*)d_in[32];
    const float* fu_b2    = (const float*)d_in[33];
    float* out = (float*)d_out;

    // ws layout (bytes)
    const size_t PB = (size_t)Nn*Cc*HW*4;       // 37,748,736 (one f32 64-ch plane set)
    const size_t YB = (size_t)Nn*16*HW*4;       // 9,437,184
    char* Wb = (char*)d_ws;
    float* high            = (float*)Wb;                          // [0, PB)  f32 planar
    unsigned short* o1     = (unsigned short*)Wb;                 // aliases high (fu1 after conv3m)
    unsigned short* enh_low  = (unsigned short*)(Wb + PB);        // bf16 [n][px][64]
    unsigned short* enh_high = (unsigned short*)(Wb + PB + PB/2); // bf16 [n][px][64]
    float* y1              = (float*)(Wb + 2*PB);
    float* y2              = (float*)(Wb + 2*PB + YB);
    unsigned short* g_wt   = (unsigned short*)(Wb + 2*PB + 2*YB); // 36864 ush
    unsigned short* g_wfu1 = g_wt + 36864;                        // 16384 ush
    unsigned short* g_wfu2 = g_wfu1 + 16384;                      // 8192 ush
    float* fp    = (float*)(Wb + 2*PB + 2*YB + 131072);
    float* fsm   = fp + 256;
    float* st_hb = fsm + 2304;
    float* st_o1 = st_hb + 32;

    k_zero<<<1, 64, 0, stream>>>(st_hb, 64);
    k_wprep2<<<240, 256, 0, stream>>>(hb_w, fu_w1, fu_w2, g_wt, g_wfu1, g_wfu2);
    k_gap<<<Nn*Cc, 256, 0, stream>>>(x, fp);
    k_filter<<<Nn, 576, 0, stream>>>(fp, w_filter, gnf_g, gnf_b, fsm);
    k_lowhigh<<<Nn*PIXBLK, 256, 0, stream>>>(x, fsm, lb_w1, lb_b1, lb_a1, high, y1);
    k_dw_c<5><<<Nn*PIXBLK, 256, 0, stream>>>(y1, lb_dw1, lb_db1, lb_w2, lb_b2, lb_a2, y2);
    k_dw_c<1><<<Nn*PIXBLK, 256, 0, stream>>>(y2, lb_dw2, lb_db2, lb_w3, lb_b3, lb_a3, y1);
    k_dw3_final<<<Nn*PIXBLK, 256, 0, stream>>>(y1, lb_dw3, lb_db3, lb_w4, lb_b4, lb_a4,
                                               lb_w5, lb_b5, enh_low);
    k_hstats<<<Nn*Cc, 256, 0, stream>>>(high, st_hb);
    k_conv3m<<<Nn*4*144, 256, 0, stream>>>(high, st_hb, hb_gn_g, hb_gn_b, g_wt, hb_b, enh_high);
    k_fu1m<<<Nn*288, 256, 0, stream>>>(enh_low, enh_high, g_wfu1, fu_b1, o1, st_o1);
    k_fu2m<<<Nn*288, 256, 0, stream>>>(o1, st_o1, fu_gn_g, fu_gn_b, g_wfu2, fu_b2, out);
}

// Round 4
// 610.732 us; speedup vs baseline: 2.1602x; 1.3672x over previous
//
#include <hip/hip_runtime.h>
#include <hip/hip_bf16.h>
#include <math.h>

#define Nn 4
#define Cc 64
#define Hh 192
#define Ww 192
#define HW (Hh*Ww)          // 36864
#define PIXBLK 144          // HW/256

typedef __attribute__((ext_vector_type(4))) float f32x4;
typedef __attribute__((ext_vector_type(8))) short s16x8;

struct __align__(8) US4 { unsigned short x,y,z,w; };

static __device__ __forceinline__ unsigned short f2bf(float v){
    __hip_bfloat16 b = __float2bfloat16(v);
    return *(unsigned short*)&b;
}
static __device__ __forceinline__ float bf2f(unsigned int u){
    return __uint_as_float(u<<16);
}

// ---------------- kernel 1: global average pool ----------------
__global__ void k_gap(const float* __restrict__ x, float* __restrict__ fp){
    int nc = blockIdx.x;                     // 0..255  (n*64+c)
    const float* p = x + (size_t)nc*HW;
    float s = 0.f;
    for(int i=threadIdx.x;i<HW;i+=256) s += p[i];
    for(int o=32;o>0;o>>=1) s += __shfl_down(s,o);
    __shared__ float sm[4];
    int wid = threadIdx.x>>6, ln = threadIdx.x&63;
    if(ln==0) sm[wid]=s;
    __syncthreads();
    if(threadIdx.x==0) fp[nc] = (sm[0]+sm[1]+sm[2]+sm[3]) / (float)HW;
}

// ---------------- kernel 2: dynamic filter (matvec + GN + softmax) ----------------
__global__ void k_filter(const float* __restrict__ fp, const float* __restrict__ wf,
                         const float* __restrict__ gg, const float* __restrict__ gb,
                         float* __restrict__ fsm){
    int n = blockIdx.x;
    __shared__ float sfp[64];
    __shared__ float sfw[576];
    __shared__ float gstat[8];
    int t = threadIdx.x;                       // 0..575
    if(t<64) sfp[t] = fp[n*64+t];
    __syncthreads();
    const float* wr = wf + (size_t)t*64;
    float acc = 0.f;
    #pragma unroll 8
    for(int k=0;k<64;k++) acc += sfp[k]*wr[k];
    sfw[t] = acc;
    __syncthreads();
    if(t<4){
        float s=0.f,s2=0.f;
        for(int i=0;i<144;i++){ float v=sfw[t*144+i]; s+=v; s2+=v*v; }
        float m = s/144.f;
        gstat[t*2]   = m;
        gstat[t*2+1] = s2/144.f - m*m;
    }
    __syncthreads();
    int g = t/144;
    float m = gstat[g*2], var = gstat[g*2+1];
    float z = (acc-m)*rsqrtf(var+1e-5f)*gg[t] + gb[t];
    sfw[t] = z;
    __syncthreads();
    if(t<64){
        float mx = -1e30f;
        for(int j=0;j<9;j++) mx = fmaxf(mx, sfw[t*9+j]);
        float e[9]; float se=0.f;
        for(int j=0;j<9;j++){ e[j]=expf(sfw[t*9+j]-mx); se+=e[j]; }
        float inv = 1.f/se;
        for(int j=0;j<9;j++) fsm[((size_t)n*64+t)*9+j] = e[j]*inv;
    }
}

// ---------------- kernel 3: low/high + conv1x1(64->16)+PReLU ----------------
// high out: bf16 pixel-major [n][px][64]
__global__ void k_lowhigh(const float* __restrict__ x, const float* __restrict__ fsm,
                          const float* __restrict__ w1, const float* __restrict__ b1,
                          const float* __restrict__ a1p,
                          unsigned short* __restrict__ high, float* __restrict__ y1){
    int bid = blockIdx.x;
    int n = bid/PIXBLK;
    int pix = (bid%PIXBLK)*256 + threadIdx.x;
    int h = pix/Ww, w = pix%Ww;
    __shared__ float sf[64*9];
    __shared__ float sw[16*64];
    __shared__ float sb[16];
    for(int i=threadIdx.x;i<576;i+=256) sf[i] = fsm[(size_t)n*576+i];
    for(int i=threadIdx.x;i<1024;i+=256) sw[i] = w1[i];
    if(threadIdx.x<16) sb[threadIdx.x] = b1[threadIdx.x];
    __syncthreads();
    int rh[3], rw[3];
    #pragma unroll
    for(int k=0;k<3;k++){
        int r = h + 2*(k-1); if(r<0) r=-r; if(r>=Hh) r=2*(Hh-1)-r; rh[k]=r;
        int c = w + 2*(k-1); if(c<0) c=-c; if(c>=Ww) c=2*(Ww-1)-c; rw[k]=c;
    }
    float acc[16];
    #pragma unroll
    for(int o=0;o<16;o++) acc[o]=0.f;
    const float* xb = x + (size_t)n*Cc*HW;
    unsigned short* hout = high + ((size_t)n*HW + pix)*64;
    for(int c0=0;c0<64;c0+=8){
        unsigned int hp[4];
        #pragma unroll
        for(int j=0;j<8;j++){
            int c = c0+j;
            const float* xc = xb + (size_t)c*HW;
            float low=0.f, ctr=0.f;
            #pragma unroll
            for(int ki=0;ki<3;ki++){
                #pragma unroll
                for(int kj=0;kj<3;kj++){
                    float v = xc[rh[ki]*Ww + rw[kj]];
                    low += sf[c*9 + ki*3 + kj]*v;
                    if(ki==1 && kj==1) ctr = v;
                }
            }
            unsigned short hb16 = f2bf(ctr-low);
            if(j&1) hp[j>>1] |= ((unsigned int)hb16)<<16; else hp[j>>1] = hb16;
            #pragma unroll
            for(int o=0;o<16;o++) acc[o] += sw[o*64+c]*low;
        }
        uint4 pk; pk.x=hp[0]; pk.y=hp[1]; pk.z=hp[2]; pk.w=hp[3];
        *(uint4*)&hout[c0] = pk;
    }
    float a1 = *a1p;
    #pragma unroll
    for(int o=0;o<16;o++){
        float v = acc[o] + sb[o];
        v = v>=0.f ? v : a1*v;
        y1[((size_t)n*16 + o)*HW + pix] = v;
    }
}

// ---------------- kernels 4/5: depthwise3x3(dil) + conv1x1(16->16) + PReLU ----------------
template<int DILT>
__global__ void k_dw_c(const float* __restrict__ yin,
                       const float* __restrict__ dw, const float* __restrict__ db,
                       const float* __restrict__ wc, const float* __restrict__ bc,
                       const float* __restrict__ ap, float* __restrict__ yout){
    int bid = blockIdx.x;
    int n = bid/PIXBLK;
    int pix = (bid%PIXBLK)*256 + threadIdx.x;
    int h = pix/Ww, w = pix%Ww;
    __shared__ float sdw[16*9];
    __shared__ float swc[16*16];
    __shared__ float sdb[16], sbc[16];
    if(threadIdx.x<144) sdw[threadIdx.x] = dw[threadIdx.x];
    if(threadIdx.x>=144 && threadIdx.x<144+16){ sdb[threadIdx.x-144]=db[threadIdx.x-144]; }
    if(threadIdx.x>=160 && threadIdx.x<160+16){ sbc[threadIdx.x-160]=bc[threadIdx.x-160]; }
    for(int i=threadIdx.x;i<256;i+=256) swc[i]=wc[i];
    __syncthreads();
    float t16[16];
    const float* yb = yin + (size_t)n*16*HW;
    for(int c=0;c<16;c++){
        float s = 0.f;
        #pragma unroll
        for(int u=0;u<3;u++){
            int hh = h + DILT*(u-1);
            if(hh<0 || hh>=Hh) continue;
            #pragma unroll
            for(int v=0;v<3;v++){
                int wwi = w + DILT*(v-1);
                if(wwi<0 || wwi>=Ww) continue;
                s += yb[(size_t)c*HW + hh*Ww + wwi]*sdw[c*9+u*3+v];
            }
        }
        t16[c] = s + sdb[c];
    }
    float a = *ap;
    #pragma unroll
    for(int o=0;o<16;o++){
        float s = sbc[o];
        #pragma unroll
        for(int c=0;c<16;c++) s += swc[o*16+c]*t16[c];
        s = s>=0.f ? s : a*s;
        yout[((size_t)n*16 + o)*HW + pix] = s;
    }
}

// ---------------- kernel 6: dw3(dil3)+conv1x1+PReLU+conv1x1(16->64) -> enh_low(bf16,pix-major) ----------------
__global__ void k_dw3_final(const float* __restrict__ yin,
                            const float* __restrict__ dw, const float* __restrict__ db,
                            const float* __restrict__ w4, const float* __restrict__ b4,
                            const float* __restrict__ a4p,
                            const float* __restrict__ w5, const float* __restrict__ b5,
                            unsigned short* __restrict__ enh_low){
    int bid = blockIdx.x;
    int n = bid/PIXBLK;
    int pix = (bid%PIXBLK)*256 + threadIdx.x;
    int h = pix/Ww, w = pix%Ww;
    __shared__ float sdw[16*9];
    __shared__ float sw4[16*16];
    __shared__ float sw5[64*16];
    __shared__ float sdb[16], sb4[16], sb5[64];
    if(threadIdx.x<144) sdw[threadIdx.x]=dw[threadIdx.x];
    if(threadIdx.x<16){ sdb[threadIdx.x]=db[threadIdx.x]; sb4[threadIdx.x]=b4[threadIdx.x]; }
    if(threadIdx.x<64) sb5[threadIdx.x]=b5[threadIdx.x];
    for(int i=threadIdx.x;i<256;i+=256) sw4[i]=w4[i];
    for(int i=threadIdx.x;i<1024;i+=256) sw5[i]=w5[i];
    __syncthreads();
    float t16[16];
    const float* yb = yin + (size_t)n*16*HW;
    for(int c=0;c<16;c++){
        float s=0.f;
        #pragma unroll
        for(int u=0;u<3;u++){
            int hh = h + 3*(u-1);
            if(hh<0||hh>=Hh) continue;
            #pragma unroll
            for(int v=0;v<3;v++){
                int wwi = w + 3*(v-1);
                if(wwi<0||wwi>=Ww) continue;
                s += yb[(size_t)c*HW + hh*Ww + wwi]*sdw[c*9+u*3+v];
            }
        }
        t16[c] = s + sdb[c];
    }
    float a = *a4p;
    float y4[16];
    #pragma unroll
    for(int o=0;o<16;o++){
        float s = sb4[o];
        #pragma unroll
        for(int c=0;c<16;c++) s += sw4[o*16+c]*t16[c];
        y4[o] = s>=0.f ? s : a*s;
    }
    unsigned short* dst = enh_low + ((size_t)n*HW + pix)*64;
    #pragma unroll
    for(int ob=0;ob<64;ob+=4){
        unsigned short tmp[4];
        #pragma unroll
        for(int j=0;j<4;j++){
            int o=ob+j;
            float s = sb5[o];
            #pragma unroll
            for(int c=0;c<16;c++) s += sw5[o*16+c]*y4[c];
            tmp[j]=f2bf(s);
        }
        US4 pk; pk.x=tmp[0]; pk.y=tmp[1]; pk.z=tmp[2]; pk.w=tmp[3];
        *(US4*)&dst[ob] = pk;
    }
}

// ---------------- zero small stats ----------------
__global__ void k_zero(float* __restrict__ p, int nf){
    int i = blockIdx.x*64 + threadIdx.x;
    if(i<nf) p[i]=0.f;
}

// ---------------- kernel 7: high GN stats (bf16 pix-major input, padded st lines) ----------------
// st layout: group g -> st[g*32 + {0,1}]  (one 128B line per group)
__global__ void k_hstats(const unsigned short* __restrict__ high, float* __restrict__ st){
    int n = blockIdx.x/36, chunk = blockIdx.x%36;     // 1024 px per chunk
    const uint4* p = (const uint4*)(high + ((size_t)n*HW + chunk*1024)*64);
    int tid = threadIdx.x;
    int q = tid&7;                                    // channel octet (fixed per thread)
    float s=0.f, s2=0.f;
    for(int i=tid;i<8192;i+=256){
        uint4 v = p[i];
        unsigned int vv[4]={v.x,v.y,v.z,v.w};
        #pragma unroll
        for(int j=0;j<4;j++){
            float f0 = bf2f(vv[j]&0xffffu);
            float f1 = bf2f(vv[j]>>16);
            s += f0+f1; s2 += f0*f0+f1*f1;
        }
    }
    #pragma unroll
    for(int o=8;o<64;o<<=1){ s+=__shfl_down(s,o); s2+=__shfl_down(s2,o); }
    __shared__ float so[4][8], so2[4][8];
    int wv=tid>>6, ln=tid&63;
    if(ln<8){ so[wv][ln]=s; so2[wv][ln]=s2; }
    __syncthreads();
    __shared__ float oct[8], oct2[8];
    if(tid<8){
        oct[tid]  = so[0][tid]+so[1][tid]+so[2][tid]+so[3][tid];
        oct2[tid] = so2[0][tid]+so2[1][tid]+so2[2][tid]+so2[3][tid];
    }
    __syncthreads();
    if(tid<4){
        atomicAdd(&st[(n*4+tid)*32 + 0], oct[2*tid]+oct[2*tid+1]);
        atomicAdd(&st[(n*4+tid)*32 + 1], oct2[2*tid]+oct2[2*tid+1]);
    }
    (void)q;
}

// ---------------- weight prep: conv3 + fu1 + fu2 (bf16 + swizzle) ----------------
__global__ void k_wprep2(const float* __restrict__ hw, const float* __restrict__ fw1,
                         const float* __restrict__ fw2,
                         unsigned short* __restrict__ g_wt,
                         unsigned short* __restrict__ g_wfu1,
                         unsigned short* __restrict__ g_wfu2){
    int idx = blockIdx.x*256 + threadIdx.x;    // 0..61439
    if(idx<36864){
        int c = idx & 63;
        int o = (idx>>6) & 15;
        int t = (idx>>10) % 9;
        int og = idx / 9216;
        float v = hw[(size_t)(((og*16+o)*64)+c)*9 + t];
        g_wt[(size_t)og*9216 + (t*16+o)*64 + (c ^ ((o&7)<<3))] = f2bf(v);
    } else if(idx<53248){
        int i = idx-36864;
        int o = i>>7, c = i&127;
        g_wfu1[o*128 + (c ^ ((o&15)<<3))] = f2bf(fw1[i]);
    } else {
        int i = idx-53248;
        int o = i>>7, c = i&127;
        g_wfu2[o*128 + (c ^ ((o&15)<<3))] = f2bf(fw2[i]);
    }
}

// ---------------- kernel 8: conv3x3 64->64 via MFMA -> enh_high(bf16,pix-major) ----------------
__global__ void __launch_bounds__(256,2)
k_conv3m(const unsigned short* __restrict__ high, const float* __restrict__ st,
         const float* __restrict__ gng, const float* __restrict__ gnb,
         const unsigned short* __restrict__ g_wt, const float* __restrict__ hb,
         unsigned short* __restrict__ enh_high){
    int bid = blockIdx.x;
    int tile = bid % 144;
    int og   = (bid/144) & 3;
    int n    = bid / 576;
    int tr0 = (tile/12)*16, tc0 = (tile%12)*16;
    __shared__ __align__(16) unsigned short z_lds[324*64];     // 41472 B
    __shared__ __align__(16) unsigned short wt_lds[9*16*64];   // 18432 B
    __shared__ float ssc[64], sbi[64];
    int tid = threadIdx.x;
    {
        const uint4* src = (const uint4*)(g_wt + (size_t)og*9216);
        uint4* dst = (uint4*)wt_lds;
        for(int i=tid;i<1152;i+=256) dst[i]=src[i];
    }
    if(tid<64){
        int c=tid, g=n*4+(c>>4);
        float cnt=16.f*(float)HW;
        float m=st[g*32]/cnt, var=st[g*32+1]/cnt-m*m;
        float sc=gng[c]*rsqrtf(var+1e-5f);
        ssc[c]=sc; sbi[c]=gnb[c]-m*sc;
    }
    __syncthreads();
    const uint4* hpm = (const uint4*)(high + (size_t)n*HW*64);
    for(int e=tid;e<2592;e+=256){
        int hpx = e>>3, q = e&7;
        int hr = hpx/18, hc = hpx - hr*18;
        int gr = tr0+hr-1, gc = tc0+hc-1;
        uint4 w; w.x=0; w.y=0; w.z=0; w.w=0;
        if(gr>=0 && gr<Hh && gc>=0 && gc<Ww){
            uint4 v = hpm[(size_t)(gr*Ww+gc)*8 + q];
            unsigned int vv[4]={v.x,v.y,v.z,v.w};
            #pragma unroll
            for(int j=0;j<4;j++){
                int c = q*8 + 2*j;
                float f0 = bf2f(vv[j]&0xffffu)*ssc[c]   + sbi[c];
                float f1 = bf2f(vv[j]>>16)   *ssc[c+1] + sbi[c+1];
                f0 = f0>=0.f ? f0 : 0.01f*f0;
                f1 = f1>=0.f ? f1 : 0.01f*f1;
                vv[j] = (unsigned int)f2bf(f0) | ((unsigned int)f2bf(f1)<<16);
            }
            w.x=vv[0]; w.y=vv[1]; w.z=vv[2]; w.w=vv[3];
        }
        *(uint4*)&z_lds[hpx*64 + ((q*8) ^ ((hpx&7)<<3))] = w;
    }
    __syncthreads();
    int wv = tid>>6, ln = tid&63;
    int col = ln&15, kq = ln>>4;
    f32x4 acc[4] = {{0.f,0.f,0.f,0.f},{0.f,0.f,0.f,0.f},{0.f,0.f,0.f,0.f},{0.f,0.f,0.f,0.f}};
    #pragma unroll
    for(int t=0;t<9;t++){
        int dr = t/3 - 1, dc = t%3 - 1;
        #pragma unroll
        for(int kb=0;kb<2;kb++){
            int k0 = kb*32 + kq*8;
            const s16x8 afr = *(const s16x8*)&wt_lds[(t*16+col)*64 + (k0 ^ ((col&7)<<3))];
            #pragma unroll
            for(int rf=0;rf<4;rf++){
                int r = wv*4 + rf;
                int hpx = (r+1+dr)*18 + (col+1+dc);
                const s16x8 bfr = *(const s16x8*)&z_lds[hpx*64 + (k0 ^ ((hpx&7)<<3))];
                acc[rf] = __builtin_amdgcn_mfma_f32_16x16x32_bf16(afr, bfr, acc[rf], 0, 0, 0);
            }
        }
    }
    const unsigned short* hres = high + (size_t)n*HW*64;
    #pragma unroll
    for(int rf=0;rf<4;rf++){
        int r = wv*4 + rf;
        int gpx = (tr0+r)*Ww + (tc0+col);
        US4 rv = *(const US4*)&hres[(size_t)gpx*64 + og*16 + kq*4];
        unsigned short tmp[4];
        float rvf[4] = {bf2f(rv.x), bf2f(rv.y), bf2f(rv.z), bf2f(rv.w)};
        #pragma unroll
        for(int reg=0;reg<4;reg++){
            int oc = og*16 + kq*4 + reg;
            tmp[reg] = f2bf(acc[rf][reg] + hb[oc] + rvf[reg]);
        }
        US4 pk; pk.x=tmp[0]; pk.y=tmp[1]; pk.z=tmp[2]; pk.w=tmp[3];
        *(US4*)&enh_high[((size_t)n*HW + gpx)*64 + og*16 + kq*4] = pk;
    }
}

// ---------------- kernel 9: fusion conv1x1 128->128 via MFMA + per-block stat partials ----------------
__global__ void __launch_bounds__(256,2)
k_fu1m(const unsigned short* __restrict__ el, const unsigned short* __restrict__ eh,
       const unsigned short* __restrict__ wA, const float* __restrict__ b,
       unsigned short* __restrict__ o1, float* __restrict__ partial){
    int bid = blockIdx.x;
    int n = bid/288, pt = bid%288;
    int px0 = pt*128;
    __shared__ __align__(16) unsigned short sA[128*128];   // 32 KB
    __shared__ __align__(16) unsigned short sB[128*128];   // 32 KB
    __shared__ float sb[128];
    __shared__ float redsm[16];
    int tid = threadIdx.x;
    {
        const uint4* s=(const uint4*)wA; uint4* d=(uint4*)sA;
        for(int i=tid;i<2048;i+=256) d[i]=s[i];
    }
    if(tid<128) sb[tid]=b[tid];
    {
        const uint4* se=(const uint4*)(el + ((size_t)n*HW+px0)*64);
        const uint4* sh=(const uint4*)(eh + ((size_t)n*HW+px0)*64);
        for(int i=tid;i<2048;i+=256){
            int px=i>>4, q=i&15;
            uint4 v = (q<8)? se[px*8+q] : sh[px*8+(q-8)];
            int c0 = q*8;
            *(uint4*)&sB[px*128 + (c0 ^ ((px&15)<<3))] = v;
        }
    }
    __syncthreads();
    int wv=tid>>6, ln=tid&63;
    int wm=wv>>1, wn=wv&1;
    int col=ln&15, kq=ln>>4;
    f32x4 acc[4][4];
    #pragma unroll
    for(int m=0;m<4;m++)
        #pragma unroll
        for(int nf=0;nf<4;nf++) acc[m][nf]=(f32x4){0.f,0.f,0.f,0.f};
    #pragma unroll
    for(int kb=0;kb<4;kb++){
        int k0 = kb*32 + kq*8;
        s16x8 a[4], bf[4];
        #pragma unroll
        for(int m=0;m<4;m++)
            a[m] = *(const s16x8*)&sA[(wm*64+m*16+col)*128 + (k0 ^ (col<<3))];
        #pragma unroll
        for(int nf=0;nf<4;nf++)
            bf[nf] = *(const s16x8*)&sB[(wn*64+nf*16+col)*128 + (k0 ^ (col<<3))];
        #pragma unroll
        for(int m=0;m<4;m++)
            #pragma unroll
            for(int nf=0;nf<4;nf++)
                acc[m][nf] = __builtin_amdgcn_mfma_f32_16x16x32_bf16(a[m], bf[nf], acc[m][nf], 0,0,0);
    }
    float sg0=0.f,sq0=0.f,sg1=0.f,sq1=0.f;
    #pragma unroll
    for(int m=0;m<4;m++){
        int oc0 = wm*64 + m*16 + kq*4;
        #pragma unroll
        for(int nf=0;nf<4;nf++){
            int px = wn*64 + nf*16 + col;
            unsigned short tmp[4];
            #pragma unroll
            for(int reg=0;reg<4;reg++){
                float v = acc[m][nf][reg] + sb[oc0+reg];
                if(m<2){ sg0+=v; sq0+=v*v; } else { sg1+=v; sq1+=v*v; }
                tmp[reg]=f2bf(v);
            }
            US4 pk; pk.x=tmp[0]; pk.y=tmp[1]; pk.z=tmp[2]; pk.w=tmp[3];
            *(US4*)&o1[((size_t)n*HW + px0 + px)*128 + oc0] = pk;
        }
    }
    #pragma unroll
    for(int o=32;o>0;o>>=1){
        sg0+=__shfl_down(sg0,o); sq0+=__shfl_down(sq0,o);
        sg1+=__shfl_down(sg1,o); sq1+=__shfl_down(sq1,o);
    }
    if(ln==0){ redsm[wv*4+0]=sg0; redsm[wv*4+1]=sq0; redsm[wv*4+2]=sg1; redsm[wv*4+3]=sq1; }
    __syncthreads();
    // partial[bid*8 + gl*2 + comp], group = n*4+gl
    if(tid<8){
        int gl = tid>>1, comp = tid&1;
        int wbase = (gl>>1)*2;                 // waves {0,1} for gl 0/1, {2,3} for gl 2/3
        int off = (gl&1)*2 + comp;             // {sg0,sq0} or {sg1,sq1}
        partial[(size_t)bid*8 + tid] = redsm[wbase*4+off] + redsm[(wbase+1)*4+off];
    }
}

// ---------------- kernel 9b: reduce partials -> st_o1 (padded lines) ----------------
__global__ void k_redstats(const float* __restrict__ partial, float* __restrict__ st){
    int b = blockIdx.x;                        // 0..15 : n*4+gl
    int n = b>>2, gl = b&3;
    int tid = threadIdx.x;
    float a0=0.f, a1=0.f;
    for(int pt=tid; pt<288; pt+=256){
        size_t base = (size_t)(n*288+pt)*8 + gl*2;
        a0 += partial[base];
        a1 += partial[base+1];
    }
    #pragma unroll
    for(int o=32;o>0;o>>=1){ a0+=__shfl_down(a0,o); a1+=__shfl_down(a1,o); }
    __shared__ float sm[8];
    int wv=tid>>6, ln=tid&63;
    if(ln==0){ sm[wv*2]=a0; sm[wv*2+1]=a1; }
    __syncthreads();
    if(tid==0){
        st[b*32+0] = sm[0]+sm[2]+sm[4]+sm[6];
        st[b*32+1] = sm[1]+sm[3]+sm[5]+sm[7];
    }
}

// ---------------- kernel 10: GN + GELU + conv1x1 128->64 via MFMA -> out(f32) ----------------
__global__ void __launch_bounds__(256,2)
k_fu2m(const unsigned short* __restrict__ o1, const float* __restrict__ st,
       const float* __restrict__ gg, const float* __restrict__ gb,
       const unsigned short* __restrict__ wA, const float* __restrict__ b2,
       float* __restrict__ out){
    int bid = blockIdx.x;
    int n = bid/288, pt = bid%288;
    int px0 = pt*128;
    __shared__ __align__(16) unsigned short sA[64*128];    // 16 KB
    __shared__ __align__(16) unsigned short sB[128*128];   // 32 KB
    __shared__ float ssc[128], sbi[128], sb2[64];
    int tid = threadIdx.x;
    {
        const uint4* s=(const uint4*)wA; uint4* d=(uint4*)sA;
        for(int i=tid;i<1024;i+=256) d[i]=s[i];
    }
    if(tid<128){
        int c=tid, g=n*4+(c>>5);
        float cnt = 32.f*(float)HW;
        float m = st[g*32]/cnt;
        float var = st[g*32+1]/cnt - m*m;
        float sc = gg[c]*rsqrtf(var+1e-5f);
        ssc[c]=sc; sbi[c]=gb[c]-m*sc;
    }
    if(tid<64) sb2[tid]=b2[tid];
    __syncthreads();
    {
        const uint4* so=(const uint4*)(o1 + ((size_t)n*HW+px0)*128);
        for(int i=tid;i<2048;i+=256){
            int px=i>>4, q=i&15;
            int c0 = q*8;
            uint4 v = so[px*16+q];
            unsigned int vals[4] = {v.x,v.y,v.z,v.w};
            #pragma unroll
            for(int j=0;j<4;j++){
                int c = c0 + 2*j;
                float f0 = bf2f(vals[j]&0xffffu)*ssc[c]   + sbi[c];
                float f1 = bf2f(vals[j]>>16)   *ssc[c+1] + sbi[c+1];
                f0 = 0.5f*f0*(1.f+erff(f0*0.70710678118654752f));
                f1 = 0.5f*f1*(1.f+erff(f1*0.70710678118654752f));
                vals[j] = (unsigned int)f2bf(f0) | ((unsigned int)f2bf(f1)<<16);
            }
            uint4 w; w.x=vals[0]; w.y=vals[1]; w.z=vals[2]; w.w=vals[3];
            *(uint4*)&sB[px*128 + (c0 ^ ((px&15)<<3))] = w;
        }
    }
    __syncthreads();
    int wv=tid>>6, ln=tid&63;
    int col=ln&15, kq=ln>>4;
    f32x4 acc[4][2];
    #pragma unroll
    for(int m=0;m<4;m++){ acc[m][0]=(f32x4){0,0,0,0}; acc[m][1]=(f32x4){0,0,0,0}; }
    #pragma unroll
    for(int kb=0;kb<4;kb++){
        int k0 = kb*32 + kq*8;
        s16x8 a[4], bf[2];
        #pragma unroll
        for(int m=0;m<4;m++)
            a[m] = *(const s16x8*)&sA[(m*16+col)*128 + (k0 ^ (col<<3))];
        #pragma unroll
        for(int nf=0;nf<2;nf++)
            bf[nf] = *(const s16x8*)&sB[(wv*32+nf*16+col)*128 + (k0 ^ (col<<3))];
        #pragma unroll
        for(int m=0;m<4;m++)
            #pragma unroll
            for(int nf=0;nf<2;nf++)
                acc[m][nf] = __builtin_amdgcn_mfma_f32_16x16x32_bf16(a[m], bf[nf], acc[m][nf], 0,0,0);
    }
    #pragma unroll
    for(int m=0;m<4;m++){
        int oc0 = m*16 + kq*4;
        #pragma unroll
        for(int nf=0;nf<2;nf++){
            int px = px0 + wv*32 + nf*16 + col;
            #pragma unroll
            for(int reg=0;reg<4;reg++){
                int oc = oc0+reg;
                out[((size_t)n*64+oc)*HW + px] = acc[m][nf][reg] + sb2[oc];
            }
        }
    }
}

extern "C" void kernel_launch(void* const* d_in, const int* in_sizes, int n_in,
                              void* d_out, int out_size, void* d_ws, size_t ws_size,
                              hipStream_t stream) {
    const float* x        = (const float*)d_in[0];
    const float* w_filter = (const float*)d_in[1];
    const float* gnf_g    = (const float*)d_in[2];
    const float* gnf_b    = (const float*)d_in[3];
    const float* lb_w1    = (const float*)d_in[4];
    const float* lb_b1    = (const float*)d_in[5];
    const float* lb_a1    = (const float*)d_in[6];
    const float* lb_dw1   = (const float*)d_in[7];
    const float* lb_db1   = (const float*)d_in[8];
    const float* lb_w2    = (const float*)d_in[9];
    const float* lb_b2    = (const float*)d_in[10];
    const float* lb_a2    = (const float*)d_in[11];
    const float* lb_dw2   = (const float*)d_in[12];
    const float* lb_db2   = (const float*)d_in[13];
    const float* lb_w3    = (const float*)d_in[14];
    const float* lb_b3    = (const float*)d_in[15];
    const float* lb_a3    = (const float*)d_in[16];
    const float* lb_dw3   = (const float*)d_in[17];
    const float* lb_db3   = (const float*)d_in[18];
    const float* lb_w4    = (const float*)d_in[19];
    const float* lb_b4    = (const float*)d_in[20];
    const float* lb_a4    = (const float*)d_in[21];
    const float* lb_w5    = (const float*)d_in[22];
    const float* lb_b5    = (const float*)d_in[23];
    const float* hb_gn_g  = (const float*)d_in[24];
    const float* hb_gn_b  = (const float*)d_in[25];
    const float* hb_w     = (const float*)d_in[26];
    const float* hb_b     = (const float*)d_in[27];
    const float* fu_w1    = (const float*)d_in[28];
    const float* fu_b1    = (const float*)d_in[29];
    const float* fu_gn_g  = (const float*)d_in[30];
    const float* fu_gn_b  = (const float*)d_in[31];
    const float* fu_w2    = (const float*)d_in[32];
    const float* fu_b2    = (const float*)d_in[33];
    float* out = (float*)d_out;

    // ws layout (bytes)
    const size_t O1B = (size_t)Nn*HW*128*2;     // 37,748,736  o1 bf16 [n][px][128]
    const size_t EB  = (size_t)Nn*HW*64*2;      // 18,874,368  bf16 [n][px][64]
    const size_t YB  = (size_t)Nn*16*HW*4;      // 9,437,184   f32 planar
    char* Wb = (char*)d_ws;
    unsigned short* o1       = (unsigned short*)Wb;               // [0, O1B)
    unsigned short* high     = (unsigned short*)Wb;               // aliases o1 (dead before fu1m writes)
    unsigned short* enh_low  = (unsigned short*)(Wb + O1B);
    unsigned short* enh_high = (unsigned short*)(Wb + O1B + EB);
    float* y1                = (float*)(Wb + O1B + 2*EB);
    float* y2                = (float*)(Wb + O1B + 2*EB + YB);
    unsigned short* g_wt     = (unsigned short*)(Wb + O1B + 2*EB + 2*YB); // 36864 ush
    unsigned short* g_wfu1   = g_wt + 36864;                              // 16384 ush
    unsigned short* g_wfu2   = g_wfu1 + 16384;                            // 8192 ush
    float* fp      = (float*)(g_wfu2 + 8192);
    float* fsm     = fp + 256;
    float* st_hb   = fsm + 2304;     // 16 groups * 32 floats (padded lines)
    float* st_o1   = st_hb + 512;    // 16 groups * 32 floats
    float* partial = st_o1 + 512;    // 1152 * 8 floats

    k_zero<<<8, 64, 0, stream>>>(st_hb, 512);
    k_wprep2<<<240, 256, 0, stream>>>(hb_w, fu_w1, fu_w2, g_wt, g_wfu1, g_wfu2);
    k_gap<<<Nn*Cc, 256, 0, stream>>>(x, fp);
    k_filter<<<Nn, 576, 0, stream>>>(fp, w_filter, gnf_g, gnf_b, fsm);
    k_lowhigh<<<Nn*PIXBLK, 256, 0, stream>>>(x, fsm, lb_w1, lb_b1, lb_a1, high, y1);
    k_dw_c<5><<<Nn*PIXBLK, 256, 0, stream>>>(y1, lb_dw1, lb_db1, lb_w2, lb_b2, lb_a2, y2);
    k_dw_c<1><<<Nn*PIXBLK, 256, 0, stream>>>(y2, lb_dw2, lb_db2, lb_w3, lb_b3, lb_a3, y1);
    k_dw3_final<<<Nn*PIXBLK, 256, 0, stream>>>(y1, lb_dw3, lb_db3, lb_w4, lb_b4, lb_a4,
                                               lb_w5, lb_b5, enh_low);
    k_hstats<<<Nn*36, 256, 0, stream>>>(high, st_hb);
    k_conv3m<<<Nn*4*144, 256, 0, stream>>>(high, st_hb, hb_gn_g, hb_gn_b, g_wt, hb_b, enh_high);
    k_fu1m<<<Nn*288, 256, 0, stream>>>(enh_low, enh_high, g_wfu1, fu_b1, o1, partial);
    k_redstats<<<16, 256, 0, stream>>>(partial, st_o1);
    k_fu2m<<<Nn*288, 256, 0, stream>>>(o1, st_o1, fu_gn_g, fu_gn_b, g_wfu2, fu_b2, out);
}

// Round 5
// 536.577 us; speedup vs baseline: 2.4587x; 1.1382x over previous
//
#include <hip/hip_runtime.h>
#include <hip/hip_bf16.h>
#include <math.h>

#define Nn 4
#define Cc 64
#define Hh 192
#define Ww 192
#define HW (Hh*Ww)          // 36864
#define PIXBLK 144          // HW/256

typedef __attribute__((ext_vector_type(4))) float f32x4;
typedef __attribute__((ext_vector_type(8))) short s16x8;

struct __align__(8) US4 { unsigned short x,y,z,w; };

static __device__ __forceinline__ unsigned short f2bf(float v){
    __hip_bfloat16 b = __float2bfloat16(v);
    return *(unsigned short*)&b;
}
static __device__ __forceinline__ float bf2f(unsigned int u){
    return __uint_as_float(u<<16);
}

// ---------------- kernel 1: global average pool ----------------
__global__ void k_gap(const float* __restrict__ x, float* __restrict__ fp){
    int nc = blockIdx.x;                     // 0..255  (n*64+c)
    const float* p = x + (size_t)nc*HW;
    float s = 0.f;
    for(int i=threadIdx.x;i<HW;i+=256) s += p[i];
    for(int o=32;o>0;o>>=1) s += __shfl_down(s,o);
    __shared__ float sm[4];
    int wid = threadIdx.x>>6, ln = threadIdx.x&63;
    if(ln==0) sm[wid]=s;
    __syncthreads();
    if(threadIdx.x==0) fp[nc] = (sm[0]+sm[1]+sm[2]+sm[3]) / (float)HW;
}

// ---------------- kernel 2: dynamic filter (matvec + GN + softmax) ----------------
__global__ void k_filter(const float* __restrict__ fp, const float* __restrict__ wf,
                         const float* __restrict__ gg, const float* __restrict__ gb,
                         float* __restrict__ fsm){
    int n = blockIdx.x;
    __shared__ float sfp[64];
    __shared__ float sfw[576];
    __shared__ float gstat[8];
    int t = threadIdx.x;                       // 0..575
    if(t<64) sfp[t] = fp[n*64+t];
    __syncthreads();
    const float* wr = wf + (size_t)t*64;
    float acc = 0.f;
    #pragma unroll 8
    for(int k=0;k<64;k++) acc += sfp[k]*wr[k];
    sfw[t] = acc;
    __syncthreads();
    if(t<4){
        float s=0.f,s2=0.f;
        for(int i=0;i<144;i++){ float v=sfw[t*144+i]; s+=v; s2+=v*v; }
        float m = s/144.f;
        gstat[t*2]   = m;
        gstat[t*2+1] = s2/144.f - m*m;
    }
    __syncthreads();
    int g = t/144;
    float m = gstat[g*2], var = gstat[g*2+1];
    float z = (acc-m)*rsqrtf(var+1e-5f)*gg[t] + gb[t];
    sfw[t] = z;
    __syncthreads();
    if(t<64){
        float mx = -1e30f;
        for(int j=0;j<9;j++) mx = fmaxf(mx, sfw[t*9+j]);
        float e[9]; float se=0.f;
        for(int j=0;j<9;j++){ e[j]=expf(sfw[t*9+j]-mx); se+=e[j]; }
        float inv = 1.f/se;
        for(int j=0;j<9;j++) fsm[((size_t)n*64+t)*9+j] = e[j]*inv;
    }
}

// ---------------- kernel 3: low/high + conv1x1(64->16)+PReLU + high GN partials ----------------
// 2D tiles 32w x 16h, 2 px/thread. high out: bf16 pixel-major [n][px][64] via LDS buffer.
#define HBS 72   // highbuf stride in ushorts (144 B -> bank-balanced)
__global__ void __launch_bounds__(256,2)
k_lowhigh(const float* __restrict__ x, const float* __restrict__ fsm,
          const float* __restrict__ w1, const float* __restrict__ b1,
          const float* __restrict__ a1p,
          unsigned short* __restrict__ high, float* __restrict__ y1,
          float* __restrict__ partial){
    int bid = blockIdx.x;
    int n = bid/72, tile = bid%72;
    int h0 = (tile/6)*16, w0 = (tile%6)*32;
    int t = threadIdx.x;
    int r0 = t>>5, wl = t&31;                 // px0 = (r0, wl), px1 = (r0+8, wl)
    __shared__ __align__(16) unsigned short highbuf[512*HBS];  // 73728 B
    __shared__ float sf[64*9];
    __shared__ float sw[16*64];
    __shared__ float sb[16];
    __shared__ float redsm[4][8];
    for(int i=t;i<576;i+=256) sf[i] = fsm[(size_t)n*576+i];
    for(int i=t;i<1024;i+=256) sw[i] = w1[i];
    if(t<16) sb[t] = b1[t];
    __syncthreads();
    // reflect indices
    int rh0[3], rh1[3], rw[3];
    #pragma unroll
    for(int k=0;k<3;k++){
        int a = h0 + r0 + 2*(k-1);     if(a<0) a=-a; if(a>=Hh) a=2*(Hh-1)-a; rh0[k]=a;
        int b = h0 + r0+8 + 2*(k-1);   if(b<0) b=-b; if(b>=Hh) b=2*(Hh-1)-b; rh1[k]=b;
        int c = w0 + wl + 2*(k-1);     if(c<0) c=-c; if(c>=Ww) c=2*(Ww-1)-c; rw[k]=c;
    }
    float accA[16], accB[16];
    #pragma unroll
    for(int o=0;o<16;o++){ accA[o]=0.f; accB[o]=0.f; }
    const float* xb = x + (size_t)n*Cc*HW;
    int p0 = r0*32 + wl, p1 = (r0+8)*32 + wl;
    int wv = t>>6, ln = t&63;
    #pragma unroll 1
    for(int grp=0; grp<4; grp++){
        float sg=0.f, sq=0.f;
        #pragma unroll 1
        for(int sub=0; sub<2; sub++){
            int oct = grp*2 + sub;
            unsigned int hpA[4], hpB[4];
            #pragma unroll
            for(int j=0;j<8;j++){
                int c = oct*8 + j;
                const float* xc = xb + (size_t)c*HW;
                float lowA=0.f, lowB=0.f, ctrA=0.f, ctrB=0.f;
                #pragma unroll
                for(int ki=0;ki<3;ki++){
                    #pragma unroll
                    for(int kj=0;kj<3;kj++){
                        float f = sf[c*9 + ki*3 + kj];
                        float vA = xc[rh0[ki]*Ww + rw[kj]];
                        float vB = xc[rh1[ki]*Ww + rw[kj]];
                        lowA += f*vA; lowB += f*vB;
                        if(ki==1 && kj==1){ ctrA=vA; ctrB=vB; }
                    }
                }
                float hA = ctrA-lowA, hB = ctrB-lowB;
                sg += hA+hB; sq += hA*hA + hB*hB;
                unsigned short a16=f2bf(hA), b16=f2bf(hB);
                if(j&1){ hpA[j>>1] |= ((unsigned int)a16)<<16; hpB[j>>1] |= ((unsigned int)b16)<<16; }
                else   { hpA[j>>1] = a16; hpB[j>>1] = b16; }
                #pragma unroll
                for(int o=0;o<16;o++){
                    float f1w = sw[o*64+c];
                    accA[o] += f1w*lowA; accB[o] += f1w*lowB;
                }
            }
            uint4 pkA; pkA.x=hpA[0]; pkA.y=hpA[1]; pkA.z=hpA[2]; pkA.w=hpA[3];
            uint4 pkB; pkB.x=hpB[0]; pkB.y=hpB[1]; pkB.z=hpB[2]; pkB.w=hpB[3];
            *(uint4*)&highbuf[p0*HBS + oct*8] = pkA;
            *(uint4*)&highbuf[p1*HBS + oct*8] = pkB;
        }
        // wave reduce stats for this group
        #pragma unroll
        for(int o=32;o>0;o>>=1){ sg+=__shfl_down(sg,o); sq+=__shfl_down(sq,o); }
        if(ln==0){ redsm[wv][grp*2]=sg; redsm[wv][grp*2+1]=sq; }
    }
    // y1 (planar f32)
    float a1 = *a1p;
    #pragma unroll
    for(int o=0;o<16;o++){
        float vA = accA[o] + sb[o];
        float vB = accB[o] + sb[o];
        vA = vA>=0.f ? vA : a1*vA;
        vB = vB>=0.f ? vB : a1*vB;
        y1[((size_t)n*16 + o)*HW + (h0+r0)*Ww + w0 + wl]   = vA;
        y1[((size_t)n*16 + o)*HW + (h0+r0+8)*Ww + w0 + wl] = vB;
    }
    __syncthreads();
    // coalesced high writeout: 16 rows x 4KB
    uint4* gout = (uint4*)(high + (size_t)n*HW*64);
    #pragma unroll
    for(int r=0;r<16;r++){
        int px_l = r*32 + (t>>3);
        uint4 v = *(const uint4*)&highbuf[px_l*HBS + (t&7)*8];
        gout[((size_t)(h0+r)*Ww + w0 + (t>>3))*8 + (t&7)] = v;
    }
    // block stat partials
    if(t<8) partial[(size_t)bid*8 + t] = redsm[0][t]+redsm[1][t]+redsm[2][t]+redsm[3][t];
}

// ---------------- kernels 4/5: depthwise3x3(dil) + conv1x1(16->16) + PReLU ----------------
template<int DILT>
__global__ void k_dw_c(const float* __restrict__ yin,
                       const float* __restrict__ dw, const float* __restrict__ db,
                       const float* __restrict__ wc, const float* __restrict__ bc,
                       const float* __restrict__ ap, float* __restrict__ yout){
    int bid = blockIdx.x;
    int n = bid/PIXBLK;
    int pix = (bid%PIXBLK)*256 + threadIdx.x;
    int h = pix/Ww, w = pix%Ww;
    __shared__ float sdw[16*9];
    __shared__ float swc[16*16];
    __shared__ float sdb[16], sbc[16];
    if(threadIdx.x<144) sdw[threadIdx.x] = dw[threadIdx.x];
    if(threadIdx.x>=144 && threadIdx.x<144+16){ sdb[threadIdx.x-144]=db[threadIdx.x-144]; }
    if(threadIdx.x>=160 && threadIdx.x<160+16){ sbc[threadIdx.x-160]=bc[threadIdx.x-160]; }
    for(int i=threadIdx.x;i<256;i+=256) swc[i]=wc[i];
    __syncthreads();
    float t16[16];
    const float* yb = yin + (size_t)n*16*HW;
    for(int c=0;c<16;c++){
        float s = 0.f;
        #pragma unroll
        for(int u=0;u<3;u++){
            int hh = h + DILT*(u-1);
            if(hh<0 || hh>=Hh) continue;
            #pragma unroll
            for(int v=0;v<3;v++){
                int wwi = w + DILT*(v-1);
                if(wwi<0 || wwi>=Ww) continue;
                s += yb[(size_t)c*HW + hh*Ww + wwi]*sdw[c*9+u*3+v];
            }
        }
        t16[c] = s + sdb[c];
    }
    float a = *ap;
    #pragma unroll
    for(int o=0;o<16;o++){
        float s = sbc[o];
        #pragma unroll
        for(int c=0;c<16;c++) s += swc[o*16+c]*t16[c];
        s = s>=0.f ? s : a*s;
        yout[((size_t)n*16 + o)*HW + pix] = s;
    }
}

// ---------------- kernel 6: dw3(dil3)+conv1x1+PReLU+conv1x1(16->64) -> enh_low(bf16,pix-major) ----------------
__global__ void k_dw3_final(const float* __restrict__ yin,
                            const float* __restrict__ dw, const float* __restrict__ db,
                            const float* __restrict__ w4, const float* __restrict__ b4,
                            const float* __restrict__ a4p,
                            const float* __restrict__ w5, const float* __restrict__ b5,
                            unsigned short* __restrict__ enh_low){
    int bid = blockIdx.x;
    int n = bid/PIXBLK;
    int pix = (bid%PIXBLK)*256 + threadIdx.x;
    int h = pix/Ww, w = pix%Ww;
    __shared__ float sdw[16*9];
    __shared__ float sw4[16*16];
    __shared__ float sw5[64*16];
    __shared__ float sdb[16], sb4[16], sb5[64];
    if(threadIdx.x<144) sdw[threadIdx.x]=dw[threadIdx.x];
    if(threadIdx.x<16){ sdb[threadIdx.x]=db[threadIdx.x]; sb4[threadIdx.x]=b4[threadIdx.x]; }
    if(threadIdx.x<64) sb5[threadIdx.x]=b5[threadIdx.x];
    for(int i=threadIdx.x;i<256;i+=256) sw4[i]=w4[i];
    for(int i=threadIdx.x;i<1024;i+=256) sw5[i]=w5[i];
    __syncthreads();
    float t16[16];
    const float* yb = yin + (size_t)n*16*HW;
    for(int c=0;c<16;c++){
        float s=0.f;
        #pragma unroll
        for(int u=0;u<3;u++){
            int hh = h + 3*(u-1);
            if(hh<0||hh>=Hh) continue;
            #pragma unroll
            for(int v=0;v<3;v++){
                int wwi = w + 3*(v-1);
                if(wwi<0||wwi>=Ww) continue;
                s += yb[(size_t)c*HW + hh*Ww + wwi]*sdw[c*9+u*3+v];
            }
        }
        t16[c] = s + sdb[c];
    }
    float a = *a4p;
    float y4[16];
    #pragma unroll
    for(int o=0;o<16;o++){
        float s = sb4[o];
        #pragma unroll
        for(int c=0;c<16;c++) s += sw4[o*16+c]*t16[c];
        y4[o] = s>=0.f ? s : a*s;
    }
    unsigned short* dst = enh_low + ((size_t)n*HW + pix)*64;
    #pragma unroll
    for(int ob=0;ob<64;ob+=4){
        unsigned short tmp[4];
        #pragma unroll
        for(int j=0;j<4;j++){
            int o=ob+j;
            float s = sb5[o];
            #pragma unroll
            for(int c=0;c<16;c++) s += sw5[o*16+c]*y4[c];
            tmp[j]=f2bf(s);
        }
        US4 pk; pk.x=tmp[0]; pk.y=tmp[1]; pk.z=tmp[2]; pk.w=tmp[3];
        *(US4*)&dst[ob] = pk;
    }
}

// ---------------- reduce partials -> st (padded lines), parametrized block count ----------------
__global__ void k_redstats(const float* __restrict__ partial, float* __restrict__ st, int nblk){
    int b = blockIdx.x;                        // 0..15 : n*4+gl
    int n = b>>2, gl = b&3;
    int tid = threadIdx.x;
    float a0=0.f, a1=0.f;
    for(int pt=tid; pt<nblk; pt+=256){
        size_t base = (size_t)(n*nblk+pt)*8 + gl*2;
        a0 += partial[base];
        a1 += partial[base+1];
    }
    #pragma unroll
    for(int o=32;o>0;o>>=1){ a0+=__shfl_down(a0,o); a1+=__shfl_down(a1,o); }
    __shared__ float sm[8];
    int wv=tid>>6, ln=tid&63;
    if(ln==0){ sm[wv*2]=a0; sm[wv*2+1]=a1; }
    __syncthreads();
    if(tid==0){
        st[b*32+0] = sm[0]+sm[2]+sm[4]+sm[6];
        st[b*32+1] = sm[1]+sm[3]+sm[5]+sm[7];
    }
}

// ---------------- weight prep: conv3 + fu1 + fu2 (bf16 + swizzle) ----------------
__global__ void k_wprep2(const float* __restrict__ hw, const float* __restrict__ fw1,
                         const float* __restrict__ fw2,
                         unsigned short* __restrict__ g_wt,
                         unsigned short* __restrict__ g_wfu1,
                         unsigned short* __restrict__ g_wfu2){
    int idx = blockIdx.x*256 + threadIdx.x;    // 0..61439
    if(idx<36864){
        int c = idx & 63;
        int o = (idx>>6) & 15;
        int t = (idx>>10) % 9;
        int og = idx / 9216;
        float v = hw[(size_t)(((og*16+o)*64)+c)*9 + t];
        g_wt[(size_t)og*9216 + (t*16+o)*64 + (c ^ ((o&7)<<3))] = f2bf(v);
    } else if(idx<53248){
        int i = idx-36864;
        int o = i>>7, c = i&127;
        g_wfu1[o*128 + (c ^ ((o&15)<<3))] = f2bf(fw1[i]);
    } else {
        int i = idx-53248;
        int o = i>>7, c = i&127;
        g_wfu2[o*128 + (c ^ ((o&15)<<3))] = f2bf(fw2[i]);
    }
}

// ---------------- kernel 8: conv3x3 64->64 via MFMA -> enh_high(bf16,pix-major) ----------------
__global__ void __launch_bounds__(256,2)
k_conv3m(const unsigned short* __restrict__ high, const float* __restrict__ st,
         const float* __restrict__ gng, const float* __restrict__ gnb,
         const unsigned short* __restrict__ g_wt, const float* __restrict__ hb,
         unsigned short* __restrict__ enh_high){
    int bid = blockIdx.x;
    int tile = bid % 144;
    int og   = (bid/144) & 3;
    int n    = bid / 576;
    int tr0 = (tile/12)*16, tc0 = (tile%12)*16;
    __shared__ __align__(16) unsigned short z_lds[324*64];     // 41472 B
    __shared__ __align__(16) unsigned short wt_lds[9*16*64];   // 18432 B
    __shared__ float ssc[64], sbi[64];
    int tid = threadIdx.x;
    {
        const uint4* src = (const uint4*)(g_wt + (size_t)og*9216);
        uint4* dst = (uint4*)wt_lds;
        for(int i=tid;i<1152;i+=256) dst[i]=src[i];
    }
    if(tid<64){
        int c=tid, g=n*4+(c>>4);
        float cnt=16.f*(float)HW;
        float m=st[g*32]/cnt, var=st[g*32+1]/cnt-m*m;
        float sc=gng[c]*rsqrtf(var+1e-5f);
        ssc[c]=sc; sbi[c]=gnb[c]-m*sc;
    }
    __syncthreads();
    const uint4* hpm = (const uint4*)(high + (size_t)n*HW*64);
    for(int e=tid;e<2592;e+=256){
        int hpx = e>>3, q = e&7;
        int hr = hpx/18, hc = hpx - hr*18;
        int gr = tr0+hr-1, gc = tc0+hc-1;
        uint4 w; w.x=0; w.y=0; w.z=0; w.w=0;
        if(gr>=0 && gr<Hh && gc>=0 && gc<Ww){
            uint4 v = hpm[(size_t)(gr*Ww+gc)*8 + q];
            unsigned int vv[4]={v.x,v.y,v.z,v.w};
            #pragma unroll
            for(int j=0;j<4;j++){
                int c = q*8 + 2*j;
                float f0 = bf2f(vv[j]&0xffffu)*ssc[c]   + sbi[c];
                float f1 = bf2f(vv[j]>>16)   *ssc[c+1] + sbi[c+1];
                f0 = f0>=0.f ? f0 : 0.01f*f0;
                f1 = f1>=0.f ? f1 : 0.01f*f1;
                vv[j] = (unsigned int)f2bf(f0) | ((unsigned int)f2bf(f1)<<16);
            }
            w.x=vv[0]; w.y=vv[1]; w.z=vv[2]; w.w=vv[3];
        }
        *(uint4*)&z_lds[hpx*64 + ((q*8) ^ ((hpx&7)<<3))] = w;
    }
    __syncthreads();
    int wv = tid>>6, ln = tid&63;
    int col = ln&15, kq = ln>>4;
    f32x4 acc[4] = {{0.f,0.f,0.f,0.f},{0.f,0.f,0.f,0.f},{0.f,0.f,0.f,0.f},{0.f,0.f,0.f,0.f}};
    #pragma unroll
    for(int t=0;t<9;t++){
        int dr = t/3 - 1, dc = t%3 - 1;
        #pragma unroll
        for(int kb=0;kb<2;kb++){
            int k0 = kb*32 + kq*8;
            const s16x8 afr = *(const s16x8*)&wt_lds[(t*16+col)*64 + (k0 ^ ((col&7)<<3))];
            #pragma unroll
            for(int rf=0;rf<4;rf++){
                int r = wv*4 + rf;
                int hpx = (r+1+dr)*18 + (col+1+dc);
                const s16x8 bfr = *(const s16x8*)&z_lds[hpx*64 + (k0 ^ ((hpx&7)<<3))];
                acc[rf] = __builtin_amdgcn_mfma_f32_16x16x32_bf16(afr, bfr, acc[rf], 0, 0, 0);
            }
        }
    }
    const unsigned short* hres = high + (size_t)n*HW*64;
    #pragma unroll
    for(int rf=0;rf<4;rf++){
        int r = wv*4 + rf;
        int gpx = (tr0+r)*Ww + (tc0+col);
        US4 rv = *(const US4*)&hres[(size_t)gpx*64 + og*16 + kq*4];
        unsigned short tmp[4];
        float rvf[4] = {bf2f(rv.x), bf2f(rv.y), bf2f(rv.z), bf2f(rv.w)};
        #pragma unroll
        for(int reg=0;reg<4;reg++){
            int oc = og*16 + kq*4 + reg;
            tmp[reg] = f2bf(acc[rf][reg] + hb[oc] + rvf[reg]);
        }
        US4 pk; pk.x=tmp[0]; pk.y=tmp[1]; pk.z=tmp[2]; pk.w=tmp[3];
        *(US4*)&enh_high[((size_t)n*HW + gpx)*64 + og*16 + kq*4] = pk;
    }
}

// ---------------- kernel 9: fusion conv1x1 128->128 via MFMA + per-block stat partials ----------------
__global__ void __launch_bounds__(256,2)
k_fu1m(const unsigned short* __restrict__ el, const unsigned short* __restrict__ eh,
       const unsigned short* __restrict__ wA, const float* __restrict__ b,
       unsigned short* __restrict__ o1, float* __restrict__ partial){
    int bid = blockIdx.x;
    int n = bid/288, pt = bid%288;
    int px0 = pt*128;
    __shared__ __align__(16) unsigned short sA[128*128];   // 32 KB
    __shared__ __align__(16) unsigned short sB[128*128];   // 32 KB
    __shared__ float sb[128];
    __shared__ float redsm[16];
    int tid = threadIdx.x;
    {
        const uint4* s=(const uint4*)wA; uint4* d=(uint4*)sA;
        for(int i=tid;i<2048;i+=256) d[i]=s[i];
    }
    if(tid<128) sb[tid]=b[tid];
    {
        const uint4* se=(const uint4*)(el + ((size_t)n*HW+px0)*64);
        const uint4* sh=(const uint4*)(eh + ((size_t)n*HW+px0)*64);
        for(int i=tid;i<2048;i+=256){
            int px=i>>4, q=i&15;
            uint4 v = (q<8)? se[px*8+q] : sh[px*8+(q-8)];
            int c0 = q*8;
            *(uint4*)&sB[px*128 + (c0 ^ ((px&15)<<3))] = v;
        }
    }
    __syncthreads();
    int wv=tid>>6, ln=tid&63;
    int wm=wv>>1, wn=wv&1;
    int col=ln&15, kq=ln>>4;
    f32x4 acc[4][4];
    #pragma unroll
    for(int m=0;m<4;m++)
        #pragma unroll
        for(int nf=0;nf<4;nf++) acc[m][nf]=(f32x4){0.f,0.f,0.f,0.f};
    #pragma unroll
    for(int kb=0;kb<4;kb++){
        int k0 = kb*32 + kq*8;
        s16x8 a[4], bf[4];
        #pragma unroll
        for(int m=0;m<4;m++)
            a[m] = *(const s16x8*)&sA[(wm*64+m*16+col)*128 + (k0 ^ (col<<3))];
        #pragma unroll
        for(int nf=0;nf<4;nf++)
            bf[nf] = *(const s16x8*)&sB[(wn*64+nf*16+col)*128 + (k0 ^ (col<<3))];
        #pragma unroll
        for(int m=0;m<4;m++)
            #pragma unroll
            for(int nf=0;nf<4;nf++)
                acc[m][nf] = __builtin_amdgcn_mfma_f32_16x16x32_bf16(a[m], bf[nf], acc[m][nf], 0,0,0);
    }
    float sg0=0.f,sq0=0.f,sg1=0.f,sq1=0.f;
    #pragma unroll
    for(int m=0;m<4;m++){
        int oc0 = wm*64 + m*16 + kq*4;
        #pragma unroll
        for(int nf=0;nf<4;nf++){
            int px = wn*64 + nf*16 + col;
            unsigned short tmp[4];
            #pragma unroll
            for(int reg=0;reg<4;reg++){
                float v = acc[m][nf][reg] + sb[oc0+reg];
                if(m<2){ sg0+=v; sq0+=v*v; } else { sg1+=v; sq1+=v*v; }
                tmp[reg]=f2bf(v);
            }
            US4 pk; pk.x=tmp[0]; pk.y=tmp[1]; pk.z=tmp[2]; pk.w=tmp[3];
            *(US4*)&o1[((size_t)n*HW + px0 + px)*128 + oc0] = pk;
        }
    }
    #pragma unroll
    for(int o=32;o>0;o>>=1){
        sg0+=__shfl_down(sg0,o); sq0+=__shfl_down(sq0,o);
        sg1+=__shfl_down(sg1,o); sq1+=__shfl_down(sq1,o);
    }
    if(ln==0){ redsm[wv*4+0]=sg0; redsm[wv*4+1]=sq0; redsm[wv*4+2]=sg1; redsm[wv*4+3]=sq1; }
    __syncthreads();
    if(tid<8){
        int gl = tid>>1, comp = tid&1;
        int wbase = (gl>>1)*2;
        int off = (gl&1)*2 + comp;
        partial[(size_t)bid*8 + tid] = redsm[wbase*4+off] + redsm[(wbase+1)*4+off];
    }
}

// ---------------- kernel 10: GN + GELU + conv1x1 128->64 via MFMA -> out(f32) ----------------
__global__ void __launch_bounds__(256,2)
k_fu2m(const unsigned short* __restrict__ o1, const float* __restrict__ st,
       const float* __restrict__ gg, const float* __restrict__ gb,
       const unsigned short* __restrict__ wA, const float* __restrict__ b2,
       float* __restrict__ out){
    int bid = blockIdx.x;
    int n = bid/288, pt = bid%288;
    int px0 = pt*128;
    __shared__ __align__(16) unsigned short sA[64*128];    // 16 KB
    __shared__ __align__(16) unsigned short sB[128*128];   // 32 KB
    __shared__ float ssc[128], sbi[128], sb2[64];
    int tid = threadIdx.x;
    {
        const uint4* s=(const uint4*)wA; uint4* d=(uint4*)sA;
        for(int i=tid;i<1024;i+=256) d[i]=s[i];
    }
    if(tid<128){
        int c=tid, g=n*4+(c>>5);
        float cnt = 32.f*(float)HW;
        float m = st[g*32]/cnt;
        float var = st[g*32+1]/cnt - m*m;
        float sc = gg[c]*rsqrtf(var+1e-5f);
        ssc[c]=sc; sbi[c]=gb[c]-m*sc;
    }
    if(tid<64) sb2[tid]=b2[tid];
    __syncthreads();
    {
        const uint4* so=(const uint4*)(o1 + ((size_t)n*HW+px0)*128);
        for(int i=tid;i<2048;i+=256){
            int px=i>>4, q=i&15;
            int c0 = q*8;
            uint4 v = so[px*16+q];
            unsigned int vals[4] = {v.x,v.y,v.z,v.w};
            #pragma unroll
            for(int j=0;j<4;j++){
                int c = c0 + 2*j;
                float f0 = bf2f(vals[j]&0xffffu)*ssc[c]   + sbi[c];
                float f1 = bf2f(vals[j]>>16)   *ssc[c+1] + sbi[c+1];
                f0 = 0.5f*f0*(1.f+erff(f0*0.70710678118654752f));
                f1 = 0.5f*f1*(1.f+erff(f1*0.70710678118654752f));
                vals[j] = (unsigned int)f2bf(f0) | ((unsigned int)f2bf(f1)<<16);
            }
            uint4 w; w.x=vals[0]; w.y=vals[1]; w.z=vals[2]; w.w=vals[3];
            *(uint4*)&sB[px*128 + (c0 ^ ((px&15)<<3))] = w;
        }
    }
    __syncthreads();
    int wv=tid>>6, ln=tid&63;
    int col=ln&15, kq=ln>>4;
    f32x4 acc[4][2];
    #pragma unroll
    for(int m=0;m<4;m++){ acc[m][0]=(f32x4){0,0,0,0}; acc[m][1]=(f32x4){0,0,0,0}; }
    #pragma unroll
    for(int kb=0;kb<4;kb++){
        int k0 = kb*32 + kq*8;
        s16x8 a[4], bf[2];
        #pragma unroll
        for(int m=0;m<4;m++)
            a[m] = *(const s16x8*)&sA[(m*16+col)*128 + (k0 ^ (col<<3))];
        #pragma unroll
        for(int nf=0;nf<2;nf++)
            bf[nf] = *(const s16x8*)&sB[(wv*32+nf*16+col)*128 + (k0 ^ (col<<3))];
        #pragma unroll
        for(int m=0;m<4;m++)
            #pragma unroll
            for(int nf=0;nf<2;nf++)
                acc[m][nf] = __builtin_amdgcn_mfma_f32_16x16x32_bf16(a[m], bf[nf], acc[m][nf], 0,0,0);
    }
    #pragma unroll
    for(int m=0;m<4;m++){
        int oc0 = m*16 + kq*4;
        #pragma unroll
        for(int nf=0;nf<2;nf++){
            int px = px0 + wv*32 + nf*16 + col;
            #pragma unroll
            for(int reg=0;reg<4;reg++){
                int oc = oc0+reg;
                out[((size_t)n*64+oc)*HW + px] = acc[m][nf][reg] + sb2[oc];
            }
        }
    }
}

extern "C" void kernel_launch(void* const* d_in, const int* in_sizes, int n_in,
                              void* d_out, int out_size, void* d_ws, size_t ws_size,
                              hipStream_t stream) {
    const float* x        = (const float*)d_in[0];
    const float* w_filter = (const float*)d_in[1];
    const float* gnf_g    = (const float*)d_in[2];
    const float* gnf_b    = (const float*)d_in[3];
    const float* lb_w1    = (const float*)d_in[4];
    const float* lb_b1    = (const float*)d_in[5];
    const float* lb_a1    = (const float*)d_in[6];
    const float* lb_dw1   = (const float*)d_in[7];
    const float* lb_db1   = (const float*)d_in[8];
    const float* lb_w2    = (const float*)d_in[9];
    const float* lb_b2    = (const float*)d_in[10];
    const float* lb_a2    = (const float*)d_in[11];
    const float* lb_dw2   = (const float*)d_in[12];
    const float* lb_db2   = (const float*)d_in[13];
    const float* lb_w3    = (const float*)d_in[14];
    const float* lb_b3    = (const float*)d_in[15];
    const float* lb_a3    = (const float*)d_in[16];
    const float* lb_dw3   = (const float*)d_in[17];
    const float* lb_db3   = (const float*)d_in[18];
    const float* lb_w4    = (const float*)d_in[19];
    const float* lb_b4    = (const float*)d_in[20];
    const float* lb_a4    = (const float*)d_in[21];
    const float* lb_w5    = (const float*)d_in[22];
    const float* lb_b5    = (const float*)d_in[23];
    const float* hb_gn_g  = (const float*)d_in[24];
    const float* hb_gn_b  = (const float*)d_in[25];
    const float* hb_w     = (const float*)d_in[26];
    const float* hb_b     = (const float*)d_in[27];
    const float* fu_w1    = (const float*)d_in[28];
    const float* fu_b1    = (const float*)d_in[29];
    const float* fu_gn_g  = (const float*)d_in[30];
    const float* fu_gn_b  = (const float*)d_in[31];
    const float* fu_w2    = (const float*)d_in[32];
    const float* fu_b2    = (const float*)d_in[33];
    float* out = (float*)d_out;

    // ws layout (bytes)
    const size_t O1B = (size_t)Nn*HW*128*2;     // 37,748,736  o1 bf16 [n][px][128]
    const size_t EB  = (size_t)Nn*HW*64*2;      // 18,874,368  bf16 [n][px][64]
    const size_t YB  = (size_t)Nn*16*HW*4;      // 9,437,184   f32 planar
    char* Wb = (char*)d_ws;
    unsigned short* o1       = (unsigned short*)Wb;               // [0, O1B)
    unsigned short* high     = (unsigned short*)Wb;               // aliases o1 (dead before fu1m writes)
    unsigned short* enh_low  = (unsigned short*)(Wb + O1B);
    unsigned short* enh_high = (unsigned short*)(Wb + O1B + EB);
    float* y1                = (float*)(Wb + O1B + 2*EB);
    float* y2                = (float*)(Wb + O1B + 2*EB + YB);
    unsigned short* g_wt     = (unsigned short*)(Wb + O1B + 2*EB + 2*YB); // 36864 ush
    unsigned short* g_wfu1   = g_wt + 36864;                              // 16384 ush
    unsigned short* g_wfu2   = g_wfu1 + 16384;                            // 8192 ush
    float* fp      = (float*)(g_wfu2 + 8192);
    float* fsm     = fp + 256;
    float* st_hb   = fsm + 2304;       // 16 groups * 32 floats (padded lines)
    float* st_o1   = st_hb + 512;      // 16 groups * 32 floats
    float* part_hb = st_o1 + 512;      // 288 * 8 floats
    float* part_o1 = part_hb + 2304;   // 1152 * 8 floats

    k_wprep2<<<240, 256, 0, stream>>>(hb_w, fu_w1, fu_w2, g_wt, g_wfu1, g_wfu2);
    k_gap<<<Nn*Cc, 256, 0, stream>>>(x, fp);
    k_filter<<<Nn, 576, 0, stream>>>(fp, w_filter, gnf_g, gnf_b, fsm);
    k_lowhigh<<<Nn*72, 256, 0, stream>>>(x, fsm, lb_w1, lb_b1, lb_a1, high, y1, part_hb);
    k_redstats<<<16, 256, 0, stream>>>(part_hb, st_hb, 72);
    k_dw_c<5><<<Nn*PIXBLK, 256, 0, stream>>>(y1, lb_dw1, lb_db1, lb_w2, lb_b2, lb_a2, y2);
    k_dw_c<1><<<Nn*PIXBLK, 256, 0, stream>>>(y2, lb_dw2, lb_db2, lb_w3, lb_b3, lb_a3, y1);
    k_dw3_final<<<Nn*PIXBLK, 256, 0, stream>>>(y1, lb_dw3, lb_db3, lb_w4, lb_b4, lb_a4,
                                               lb_w5, lb_b5, enh_low);
    k_conv3m<<<Nn*4*144, 256, 0, stream>>>(high, st_hb, hb_gn_g, hb_gn_b, g_wt, hb_b, enh_high);
    k_fu1m<<<Nn*288, 256, 0, stream>>>(enh_low, enh_high, g_wfu1, fu_b1, o1, part_o1);
    k_redstats<<<16, 256, 0, stream>>>(part_o1, st_o1, 288);
    k_fu2m<<<Nn*288, 256, 0, stream>>>(o1, st_o1, fu_gn_g, fu_gn_b, g_wfu2, fu_b2, out);
}

// Round 6
// 506.890 us; speedup vs baseline: 2.6027x; 1.0586x over previous
//
#include <hip/hip_runtime.h>
#include <hip/hip_bf16.h>
#include <math.h>

#define Nn 4
#define Cc 64
#define Hh 192
#define Ww 192
#define HW (Hh*Ww)          // 36864
#define PIXBLK 144          // HW/256

typedef __attribute__((ext_vector_type(4))) float f32x4;
typedef __attribute__((ext_vector_type(8))) short s16x8;

struct __align__(8) US4 { unsigned short x,y,z,w; };

static __device__ __forceinline__ unsigned short f2bf(float v){
    __hip_bfloat16 b = __float2bfloat16(v);
    return *(unsigned short*)&b;
}
static __device__ __forceinline__ float bf2f(unsigned int u){
    return __uint_as_float(u<<16);
}

// ---------------- kernel 1: weight prep (240 blocks) + global average pool (256 blocks) ----------------
// g_wt LINEAR layout: ((og*9+t)*16+o)*64 + c   (no swizzle; read direct to regs in conv3m)
// fu1/fu2 swizzled for LDS: o*128 + (c ^ ((o&15)<<3))
__global__ void k_prep(const float* __restrict__ hw, const float* __restrict__ fw1,
                       const float* __restrict__ fw2, const float* __restrict__ x,
                       unsigned short* __restrict__ g_wt,
                       unsigned short* __restrict__ g_wfu1,
                       unsigned short* __restrict__ g_wfu2,
                       float* __restrict__ fp){
    int b = blockIdx.x;
    __shared__ float sm[4];
    if(b < 240){
        int idx = b*256 + threadIdx.x;    // 0..61439
        if(idx<36864){
            int og = idx/9216, r = idx%9216;
            int t = r/1024, r2 = r%1024;
            int o = r2>>6, c = r2&63;
            g_wt[idx] = f2bf(hw[(size_t)(((og*16+o)*64)+c)*9 + t]);
        } else if(idx<53248){
            int i = idx-36864;
            int o = i>>7, c = i&127;
            g_wfu1[o*128 + (c ^ ((o&15)<<3))] = f2bf(fw1[i]);
        } else {
            int i = idx-53248;
            int o = i>>7, c = i&127;
            g_wfu2[o*128 + (c ^ ((o&15)<<3))] = f2bf(fw2[i]);
        }
    } else {
        int nc = b-240;                    // 0..255
        const float4* p = (const float4*)(x + (size_t)nc*HW);
        float s = 0.f;
        for(int i=threadIdx.x;i<HW/4;i+=256){ float4 v=p[i]; s += v.x+v.y+v.z+v.w; }
        for(int o=32;o>0;o>>=1) s += __shfl_down(s,o);
        int wid = threadIdx.x>>6, ln = threadIdx.x&63;
        if(ln==0) sm[wid]=s;
        __syncthreads();
        if(threadIdx.x==0) fp[nc] = (sm[0]+sm[1]+sm[2]+sm[3]) / (float)HW;
    }
}

// ---------------- kernel 2: dynamic filter (matvec + GN + softmax) ----------------
__global__ void k_filter(const float* __restrict__ fp, const float* __restrict__ wf,
                         const float* __restrict__ gg, const float* __restrict__ gb,
                         float* __restrict__ fsm){
    int n = blockIdx.x;
    __shared__ float sfp[64];
    __shared__ float sfw[576];
    __shared__ float gstat[8];
    int t = threadIdx.x;                       // 0..575
    if(t<64) sfp[t] = fp[n*64+t];
    __syncthreads();
    const float* wr = wf + (size_t)t*64;
    float acc = 0.f;
    #pragma unroll 8
    for(int k=0;k<64;k++) acc += sfp[k]*wr[k];
    sfw[t] = acc;
    __syncthreads();
    if(t<4){
        float s=0.f,s2=0.f;
        for(int i=0;i<144;i++){ float v=sfw[t*144+i]; s+=v; s2+=v*v; }
        float m = s/144.f;
        gstat[t*2]   = m;
        gstat[t*2+1] = s2/144.f - m*m;
    }
    __syncthreads();
    int g = t/144;
    float m = gstat[g*2], var = gstat[g*2+1];
    float z = (acc-m)*rsqrtf(var+1e-5f)*gg[t] + gb[t];
    sfw[t] = z;
    __syncthreads();
    if(t<64){
        float mx = -1e30f;
        for(int j=0;j<9;j++) mx = fmaxf(mx, sfw[t*9+j]);
        float e[9]; float se=0.f;
        for(int j=0;j<9;j++){ e[j]=expf(sfw[t*9+j]-mx); se+=e[j]; }
        float inv = 1.f/se;
        for(int j=0;j<9;j++) fsm[((size_t)n*64+t)*9+j] = e[j]*inv;
    }
}

// ---------------- kernel 3: low/high + conv1x1(64->16)+PReLU + high GN partials ----------------
// 16x16 tiles, 1 px/thread, 576 blocks. highbuf stride 88 ush: 88*2/4 = 44 == 12 mod 32,
// 12*k mod 32 cycles through 8 distinct 4-bank starts covering all 32 banks -> conflict-free b128.
#define HBS 88
__global__ void __launch_bounds__(256,3)
k_lowhigh(const float* __restrict__ x, const float* __restrict__ fsm,
          const float* __restrict__ w1, const float* __restrict__ b1,
          const float* __restrict__ a1p,
          unsigned short* __restrict__ high, float* __restrict__ y1,
          float* __restrict__ partial){
    int bid = blockIdx.x;
    int n = bid/144, tile = bid%144;
    int h0 = (tile/12)*16, w0 = (tile%12)*16;
    int t = threadIdx.x;
    int r0 = t>>4, wl = t&15;                  // this thread's pixel
    __shared__ __align__(16) unsigned short highbuf[256*HBS];  // 45056 B
    __shared__ float sf[576];
    __shared__ float sw[1024];
    __shared__ float sb[16];
    __shared__ float redsm[4][8];
    for(int i=t;i<576;i+=256) sf[i] = fsm[(size_t)n*576+i];
    for(int i=t;i<1024;i+=256) sw[i] = w1[i];
    if(t<16) sb[t] = b1[t];
    __syncthreads();
    int rh[3], rw[3];
    #pragma unroll
    for(int k=0;k<3;k++){
        int a = h0 + r0 + 2*(k-1); if(a<0) a=-a; if(a>=Hh) a=2*(Hh-1)-a; rh[k]=a;
        int c = w0 + wl + 2*(k-1); if(c<0) c=-c; if(c>=Ww) c=2*(Ww-1)-c; rw[k]=c;
    }
    float acc[16];
    #pragma unroll
    for(int o=0;o<16;o++) acc[o]=0.f;
    const float* xb = x + (size_t)n*Cc*HW;
    int wv = t>>6, ln = t&63;
    #pragma unroll 1
    for(int grp=0; grp<4; grp++){
        float sg=0.f, sq=0.f;
        #pragma unroll 1
        for(int sub=0; sub<2; sub++){
            int oct = grp*2 + sub;
            unsigned int hp[4];
            #pragma unroll
            for(int j=0;j<8;j++){
                int c = oct*8 + j;
                const float* xc = xb + (size_t)c*HW;
                float low=0.f, ctr=0.f;
                #pragma unroll
                for(int ki=0;ki<3;ki++){
                    #pragma unroll
                    for(int kj=0;kj<3;kj++){
                        float v = xc[rh[ki]*Ww + rw[kj]];
                        low += sf[c*9 + ki*3 + kj]*v;
                        if(ki==1 && kj==1) ctr = v;
                    }
                }
                float hv = ctr-low;
                sg += hv; sq += hv*hv;
                unsigned short h16 = f2bf(hv);
                if(j&1) hp[j>>1] |= ((unsigned int)h16)<<16; else hp[j>>1] = h16;
                #pragma unroll
                for(int o=0;o<16;o++) acc[o] += sw[o*64+c]*low;
            }
            uint4 pk; pk.x=hp[0]; pk.y=hp[1]; pk.z=hp[2]; pk.w=hp[3];
            *(uint4*)&highbuf[t*HBS + oct*8] = pk;
        }
        #pragma unroll
        for(int o=32;o>0;o>>=1){ sg+=__shfl_down(sg,o); sq+=__shfl_down(sq,o); }
        if(ln==0){ redsm[wv][grp*2]=sg; redsm[wv][grp*2+1]=sq; }
    }
    float a1 = *a1p;
    #pragma unroll
    for(int o=0;o<16;o++){
        float v = acc[o] + sb[o];
        v = v>=0.f ? v : a1*v;
        y1[((size_t)n*16 + o)*HW + (h0+r0)*Ww + w0 + wl] = v;
    }
    __syncthreads();
    // coalesced writeout: 2048 uint4 = 256 px * 128 B
    uint4* gout = (uint4*)(high + (size_t)n*HW*64);
    #pragma unroll
    for(int it=0;it<8;it++){
        int i = it*256 + t;
        int px = i>>3, sl = i&7;
        uint4 v = *(const uint4*)&highbuf[px*HBS + sl*8];
        gout[((size_t)(h0+(px>>4))*Ww + w0 + (px&15))*8 + sl] = v;
    }
    if(t<8) partial[(size_t)bid*8 + t] = redsm[0][t]+redsm[1][t]+redsm[2][t]+redsm[3][t];
}

// ---------------- kernels 4/5: depthwise3x3(dil) + conv1x1(16->16) + PReLU ----------------
template<int DILT>
__global__ void k_dw_c(const float* __restrict__ yin,
                       const float* __restrict__ dw, const float* __restrict__ db,
                       const float* __restrict__ wc, const float* __restrict__ bc,
                       const float* __restrict__ ap, float* __restrict__ yout){
    int bid = blockIdx.x;
    int n = bid/PIXBLK;
    int pix = (bid%PIXBLK)*256 + threadIdx.x;
    int h = pix/Ww, w = pix%Ww;
    __shared__ float sdw[16*9];
    __shared__ float swc[16*16];
    __shared__ float sdb[16], sbc[16];
    if(threadIdx.x<144) sdw[threadIdx.x] = dw[threadIdx.x];
    if(threadIdx.x>=144 && threadIdx.x<144+16){ sdb[threadIdx.x-144]=db[threadIdx.x-144]; }
    if(threadIdx.x>=160 && threadIdx.x<160+16){ sbc[threadIdx.x-160]=bc[threadIdx.x-160]; }
    for(int i=threadIdx.x;i<256;i+=256) swc[i]=wc[i];
    __syncthreads();
    float t16[16];
    const float* yb = yin + (size_t)n*16*HW;
    for(int c=0;c<16;c++){
        float s = 0.f;
        #pragma unroll
        for(int u=0;u<3;u++){
            int hh = h + DILT*(u-1);
            if(hh<0 || hh>=Hh) continue;
            #pragma unroll
            for(int v=0;v<3;v++){
                int wwi = w + DILT*(v-1);
                if(wwi<0 || wwi>=Ww) continue;
                s += yb[(size_t)c*HW + hh*Ww + wwi]*sdw[c*9+u*3+v];
            }
        }
        t16[c] = s + sdb[c];
    }
    float a = *ap;
    #pragma unroll
    for(int o=0;o<16;o++){
        float s = sbc[o];
        #pragma unroll
        for(int c=0;c<16;c++) s += swc[o*16+c]*t16[c];
        s = s>=0.f ? s : a*s;
        yout[((size_t)n*16 + o)*HW + pix] = s;
    }
}

// ---------------- kernel 6: dw3(dil3)+conv1x1+PReLU+conv1x1(16->64) -> enh_low(bf16,pix-major) ----------------
__global__ void k_dw3_final(const float* __restrict__ yin,
                            const float* __restrict__ dw, const float* __restrict__ db,
                            const float* __restrict__ w4, const float* __restrict__ b4,
                            const float* __restrict__ a4p,
                            const float* __restrict__ w5, const float* __restrict__ b5,
                            unsigned short* __restrict__ enh_low){
    int bid = blockIdx.x;
    int n = bid/PIXBLK;
    int pix = (bid%PIXBLK)*256 + threadIdx.x;
    int h = pix/Ww, w = pix%Ww;
    __shared__ float sdw[16*9];
    __shared__ float sw4[16*16];
    __shared__ float sw5[64*16];
    __shared__ float sdb[16], sb4[16], sb5[64];
    if(threadIdx.x<144) sdw[threadIdx.x]=dw[threadIdx.x];
    if(threadIdx.x<16){ sdb[threadIdx.x]=db[threadIdx.x]; sb4[threadIdx.x]=b4[threadIdx.x]; }
    if(threadIdx.x<64) sb5[threadIdx.x]=b5[threadIdx.x];
    for(int i=threadIdx.x;i<256;i+=256) sw4[i]=w4[i];
    for(int i=threadIdx.x;i<1024;i+=256) sw5[i]=w5[i];
    __syncthreads();
    float t16[16];
    const float* yb = yin + (size_t)n*16*HW;
    for(int c=0;c<16;c++){
        float s=0.f;
        #pragma unroll
        for(int u=0;u<3;u++){
            int hh = h + 3*(u-1);
            if(hh<0||hh>=Hh) continue;
            #pragma unroll
            for(int v=0;v<3;v++){
                int wwi = w + 3*(v-1);
                if(wwi<0||wwi>=Ww) continue;
                s += yb[(size_t)c*HW + hh*Ww + wwi]*sdw[c*9+u*3+v];
            }
        }
        t16[c] = s + sdb[c];
    }
    float a = *a4p;
    float y4[16];
    #pragma unroll
    for(int o=0;o<16;o++){
        float s = sb4[o];
        #pragma unroll
        for(int c=0;c<16;c++) s += sw4[o*16+c]*t16[c];
        y4[o] = s>=0.f ? s : a*s;
    }
    unsigned short* dst = enh_low + ((size_t)n*HW + pix)*64;
    #pragma unroll
    for(int ob=0;ob<64;ob+=4){
        unsigned short tmp[4];
        #pragma unroll
        for(int j=0;j<4;j++){
            int o=ob+j;
            float s = sb5[o];
            #pragma unroll
            for(int c=0;c<16;c++) s += sw5[o*16+c]*y4[c];
            tmp[j]=f2bf(s);
        }
        US4 pk; pk.x=tmp[0]; pk.y=tmp[1]; pk.z=tmp[2]; pk.w=tmp[3];
        *(US4*)&dst[ob] = pk;
    }
}

// ---------------- reduce partials -> st (padded lines) ----------------
__global__ void k_redstats(const float* __restrict__ partial, float* __restrict__ st, int nblk){
    int b = blockIdx.x;                        // 0..15 : n*4+gl
    int n = b>>2, gl = b&3;
    int tid = threadIdx.x;
    float a0=0.f, a1=0.f;
    for(int pt=tid; pt<nblk; pt+=256){
        size_t base = (size_t)(n*nblk+pt)*8 + gl*2;
        a0 += partial[base];
        a1 += partial[base+1];
    }
    #pragma unroll
    for(int o=32;o>0;o>>=1){ a0+=__shfl_down(a0,o); a1+=__shfl_down(a1,o); }
    __shared__ float sm[8];
    int wv=tid>>6, ln=tid&63;
    if(ln==0){ sm[wv*2]=a0; sm[wv*2+1]=a1; }
    __syncthreads();
    if(tid==0){
        st[b*32+0] = sm[0]+sm[2]+sm[4]+sm[6];
        st[b*32+1] = sm[1]+sm[3]+sm[5]+sm[7];
    }
}

// ---------------- kernel 8: conv3x3 64->64 via MFMA, all 64 oc per block ----------------
// 576 blocks; z staged once; weights direct global->reg (L2-hot, linear layout)
__global__ void __launch_bounds__(256,3)
k_conv3m(const unsigned short* __restrict__ high, const float* __restrict__ st,
         const float* __restrict__ gng, const float* __restrict__ gnb,
         const unsigned short* __restrict__ g_wt, const float* __restrict__ hb,
         unsigned short* __restrict__ enh_high){
    int bid = blockIdx.x;
    int n = bid/144, tile = bid%144;
    int tr0 = (tile/12)*16, tc0 = (tile%12)*16;
    __shared__ __align__(16) unsigned short z_lds[324*64];     // 41472 B
    __shared__ float ssc[64], sbi[64], sbias[64];
    int tid = threadIdx.x;
    if(tid<64){
        int c=tid, g=n*4+(c>>4);
        float cnt=16.f*(float)HW;
        float m=st[g*32]/cnt, var=st[g*32+1]/cnt-m*m;
        float sc=gng[c]*rsqrtf(var+1e-5f);
        ssc[c]=sc; sbi[c]=gnb[c]-m*sc;
        sbias[c]=hb[c];
    }
    __syncthreads();
    const uint4* hpm = (const uint4*)(high + (size_t)n*HW*64);
    for(int e=tid;e<2592;e+=256){
        int hpx = e>>3, q = e&7;
        int hr = hpx/18, hc = hpx - hr*18;
        int gr = tr0+hr-1, gc = tc0+hc-1;
        uint4 w; w.x=0; w.y=0; w.z=0; w.w=0;
        if(gr>=0 && gr<Hh && gc>=0 && gc<Ww){
            uint4 v = hpm[(size_t)(gr*Ww+gc)*8 + q];
            unsigned int vv[4]={v.x,v.y,v.z,v.w};
            #pragma unroll
            for(int j=0;j<4;j++){
                int c = q*8 + 2*j;
                float f0 = bf2f(vv[j]&0xffffu)*ssc[c]   + sbi[c];
                float f1 = bf2f(vv[j]>>16)   *ssc[c+1] + sbi[c+1];
                f0 = f0>=0.f ? f0 : 0.01f*f0;
                f1 = f1>=0.f ? f1 : 0.01f*f1;
                vv[j] = (unsigned int)f2bf(f0) | ((unsigned int)f2bf(f1)<<16);
            }
            w.x=vv[0]; w.y=vv[1]; w.z=vv[2]; w.w=vv[3];
        }
        *(uint4*)&z_lds[hpx*64 + ((q*8) ^ ((hpx&7)<<3))] = w;
    }
    __syncthreads();
    int wv = tid>>6, ln = tid&63;
    int col = ln&15, kq = ln>>4;
    f32x4 acc[4][4];                            // [og][rf]
    #pragma unroll
    for(int og=0;og<4;og++)
        #pragma unroll
        for(int rf=0;rf<4;rf++) acc[og][rf]=(f32x4){0.f,0.f,0.f,0.f};
    #pragma unroll
    for(int t=0;t<9;t++){
        int dr = t/3 - 1, dc = t%3 - 1;
        #pragma unroll
        for(int kb=0;kb<2;kb++){
            int k0 = kb*32 + kq*8;
            s16x8 afr[4];
            #pragma unroll
            for(int og=0;og<4;og++)
                afr[og] = *(const s16x8*)&g_wt[(size_t)(((og*9+t)*16+col)*64) + k0];
            #pragma unroll
            for(int rf=0;rf<4;rf++){
                int r = wv*4 + rf;
                int hpx = (r+1+dr)*18 + (col+1+dc);
                const s16x8 bfr = *(const s16x8*)&z_lds[hpx*64 + (k0 ^ ((hpx&7)<<3))];
                #pragma unroll
                for(int og=0;og<4;og++)
                    acc[og][rf] = __builtin_amdgcn_mfma_f32_16x16x32_bf16(afr[og], bfr, acc[og][rf], 0, 0, 0);
            }
        }
    }
    const unsigned short* hres = high + (size_t)n*HW*64;
    #pragma unroll
    for(int rf=0;rf<4;rf++){
        int r = wv*4 + rf;
        int gpx = (tr0+r)*Ww + (tc0+col);
        #pragma unroll
        for(int og=0;og<4;og++){
            US4 rv = *(const US4*)&hres[(size_t)gpx*64 + og*16 + kq*4];
            float rvf[4] = {bf2f(rv.x), bf2f(rv.y), bf2f(rv.z), bf2f(rv.w)};
            unsigned short tmp[4];
            #pragma unroll
            for(int reg=0;reg<4;reg++){
                int oc = og*16 + kq*4 + reg;
                tmp[reg] = f2bf(acc[og][rf][reg] + sbias[oc] + rvf[reg]);
            }
            US4 pk; pk.x=tmp[0]; pk.y=tmp[1]; pk.z=tmp[2]; pk.w=tmp[3];
            *(US4*)&enh_high[((size_t)n*HW + gpx)*64 + og*16 + kq*4] = pk;
        }
    }
}

// ---------------- kernel 9: fusion conv1x1 128->128 via MFMA + per-block stat partials ----------------
__global__ void __launch_bounds__(256,2)
k_fu1m(const unsigned short* __restrict__ el, const unsigned short* __restrict__ eh,
       const unsigned short* __restrict__ wA, const float* __restrict__ b,
       unsigned short* __restrict__ o1, float* __restrict__ partial){
    int bid = blockIdx.x;
    int n = bid/288, pt = bid%288;
    int px0 = pt*128;
    __shared__ __align__(16) unsigned short sA[128*128];   // 32 KB
    __shared__ __align__(16) unsigned short sB[128*128];   // 32 KB
    __shared__ float sb[128];
    __shared__ float redsm[16];
    int tid = threadIdx.x;
    {
        const uint4* s=(const uint4*)wA; uint4* d=(uint4*)sA;
        for(int i=tid;i<2048;i+=256) d[i]=s[i];
    }
    if(tid<128) sb[tid]=b[tid];
    {
        const uint4* se=(const uint4*)(el + ((size_t)n*HW+px0)*64);
        const uint4* sh=(const uint4*)(eh + ((size_t)n*HW+px0)*64);
        for(int i=tid;i<2048;i+=256){
            int px=i>>4, q=i&15;
            uint4 v = (q<8)? se[px*8+q] : sh[px*8+(q-8)];
            int c0 = q*8;
            *(uint4*)&sB[px*128 + (c0 ^ ((px&15)<<3))] = v;
        }
    }
    __syncthreads();
    int wv=tid>>6, ln=tid&63;
    int wm=wv>>1, wn=wv&1;
    int col=ln&15, kq=ln>>4;
    f32x4 acc[4][4];
    #pragma unroll
    for(int m=0;m<4;m++)
        #pragma unroll
        for(int nf=0;nf<4;nf++) acc[m][nf]=(f32x4){0.f,0.f,0.f,0.f};
    #pragma unroll
    for(int kb=0;kb<4;kb++){
        int k0 = kb*32 + kq*8;
        s16x8 a[4], bf[4];
        #pragma unroll
        for(int m=0;m<4;m++)
            a[m] = *(const s16x8*)&sA[(wm*64+m*16+col)*128 + (k0 ^ (col<<3))];
        #pragma unroll
        for(int nf=0;nf<4;nf++)
            bf[nf] = *(const s16x8*)&sB[(wn*64+nf*16+col)*128 + (k0 ^ (col<<3))];
        #pragma unroll
        for(int m=0;m<4;m++)
            #pragma unroll
            for(int nf=0;nf<4;nf++)
                acc[m][nf] = __builtin_amdgcn_mfma_f32_16x16x32_bf16(a[m], bf[nf], acc[m][nf], 0,0,0);
    }
    float sg0=0.f,sq0=0.f,sg1=0.f,sq1=0.f;
    #pragma unroll
    for(int m=0;m<4;m++){
        int oc0 = wm*64 + m*16 + kq*4;
        #pragma unroll
        for(int nf=0;nf<4;nf++){
            int px = wn*64 + nf*16 + col;
            unsigned short tmp[4];
            #pragma unroll
            for(int reg=0;reg<4;reg++){
                float v = acc[m][nf][reg] + sb[oc0+reg];
                if(m<2){ sg0+=v; sq0+=v*v; } else { sg1+=v; sq1+=v*v; }
                tmp[reg]=f2bf(v);
            }
            US4 pk; pk.x=tmp[0]; pk.y=tmp[1]; pk.z=tmp[2]; pk.w=tmp[3];
            *(US4*)&o1[((size_t)n*HW + px0 + px)*128 + oc0] = pk;
        }
    }
    #pragma unroll
    for(int o=32;o>0;o>>=1){
        sg0+=__shfl_down(sg0,o); sq0+=__shfl_down(sq0,o);
        sg1+=__shfl_down(sg1,o); sq1+=__shfl_down(sq1,o);
    }
    if(ln==0){ redsm[wv*4+0]=sg0; redsm[wv*4+1]=sq0; redsm[wv*4+2]=sg1; redsm[wv*4+3]=sq1; }
    __syncthreads();
    if(tid<8){
        int gl = tid>>1, comp = tid&1;
        int wbase = (gl>>1)*2;
        int off = (gl&1)*2 + comp;
        partial[(size_t)bid*8 + tid] = redsm[wbase*4+off] + redsm[(wbase+1)*4+off];
    }
}

// ---------------- kernel 10: GN + GELU + conv1x1 128->64 via MFMA -> out(f32) ----------------
__global__ void __launch_bounds__(256,2)
k_fu2m(const unsigned short* __restrict__ o1, const float* __restrict__ st,
       const float* __restrict__ gg, const float* __restrict__ gb,
       const unsigned short* __restrict__ wA, const float* __restrict__ b2,
       float* __restrict__ out){
    int bid = blockIdx.x;
    int n = bid/288, pt = bid%288;
    int px0 = pt*128;
    __shared__ __align__(16) unsigned short sA[64*128];    // 16 KB
    __shared__ __align__(16) unsigned short sB[128*128];   // 32 KB
    __shared__ float ssc[128], sbi[128], sb2[64];
    int tid = threadIdx.x;
    {
        const uint4* s=(const uint4*)wA; uint4* d=(uint4*)sA;
        for(int i=tid;i<1024;i+=256) d[i]=s[i];
    }
    if(tid<128){
        int c=tid, g=n*4+(c>>5);
        float cnt = 32.f*(float)HW;
        float m = st[g*32]/cnt;
        float var = st[g*32+1]/cnt - m*m;
        float sc = gg[c]*rsqrtf(var+1e-5f);
        ssc[c]=sc; sbi[c]=gb[c]-m*sc;
    }
    if(tid<64) sb2[tid]=b2[tid];
    __syncthreads();
    {
        const uint4* so=(const uint4*)(o1 + ((size_t)n*HW+px0)*128);
        for(int i=tid;i<2048;i+=256){
            int px=i>>4, q=i&15;
            int c0 = q*8;
            uint4 v = so[px*16+q];
            unsigned int vals[4] = {v.x,v.y,v.z,v.w};
            #pragma unroll
            for(int j=0;j<4;j++){
                int c = c0 + 2*j;
                float f0 = bf2f(vals[j]&0xffffu)*ssc[c]   + sbi[c];
                float f1 = bf2f(vals[j]>>16)   *ssc[c+1] + sbi[c+1];
                f0 = 0.5f*f0*(1.f+erff(f0*0.70710678118654752f));
                f1 = 0.5f*f1*(1.f+erff(f1*0.70710678118654752f));
                vals[j] = (unsigned int)f2bf(f0) | ((unsigned int)f2bf(f1)<<16);
            }
            uint4 w; w.x=vals[0]; w.y=vals[1]; w.z=vals[2]; w.w=vals[3];
            *(uint4*)&sB[px*128 + (c0 ^ ((px&15)<<3))] = w;
        }
    }
    __syncthreads();
    int wv=tid>>6, ln=tid&63;
    int col=ln&15, kq=ln>>4;
    f32x4 acc[4][2];
    #pragma unroll
    for(int m=0;m<4;m++){ acc[m][0]=(f32x4){0,0,0,0}; acc[m][1]=(f32x4){0,0,0,0}; }
    #pragma unroll
    for(int kb=0;kb<4;kb++){
        int k0 = kb*32 + kq*8;
        s16x8 a[4], bf[2];
        #pragma unroll
        for(int m=0;m<4;m++)
            a[m] = *(const s16x8*)&sA[(m*16+col)*128 + (k0 ^ (col<<3))];
        #pragma unroll
        for(int nf=0;nf<2;nf++)
            bf[nf] = *(const s16x8*)&sB[(wv*32+nf*16+col)*128 + (k0 ^ (col<<3))];
        #pragma unroll
        for(int m=0;m<4;m++)
            #pragma unroll
            for(int nf=0;nf<2;nf++)
                acc[m][nf] = __builtin_amdgcn_mfma_f32_16x16x32_bf16(a[m], bf[nf], acc[m][nf], 0,0,0);
    }
    #pragma unroll
    for(int m=0;m<4;m++){
        int oc0 = m*16 + kq*4;
        #pragma unroll
        for(int nf=0;nf<2;nf++){
            int px = px0 + wv*32 + nf*16 + col;
            #pragma unroll
            for(int reg=0;reg<4;reg++){
                int oc = oc0+reg;
                out[((size_t)n*64+oc)*HW + px] = acc[m][nf][reg] + sb2[oc];
            }
        }
    }
}

extern "C" void kernel_launch(void* const* d_in, const int* in_sizes, int n_in,
                              void* d_out, int out_size, void* d_ws, size_t ws_size,
                              hipStream_t stream) {
    const float* x        = (const float*)d_in[0];
    const float* w_filter = (const float*)d_in[1];
    const float* gnf_g    = (const float*)d_in[2];
    const float* gnf_b    = (const float*)d_in[3];
    const float* lb_w1    = (const float*)d_in[4];
    const float* lb_b1    = (const float*)d_in[5];
    const float* lb_a1    = (const float*)d_in[6];
    const float* lb_dw1   = (const float*)d_in[7];
    const float* lb_db1   = (const float*)d_in[8];
    const float* lb_w2    = (const float*)d_in[9];
    const float* lb_b2    = (const float*)d_in[10];
    const float* lb_a2    = (const float*)d_in[11];
    const float* lb_dw2   = (const float*)d_in[12];
    const float* lb_db2   = (const float*)d_in[13];
    const float* lb_w3    = (const float*)d_in[14];
    const float* lb_b3    = (const float*)d_in[15];
    const float* lb_a3    = (const float*)d_in[16];
    const float* lb_dw3   = (const float*)d_in[17];
    const float* lb_db3   = (const float*)d_in[18];
    const float* lb_w4    = (const float*)d_in[19];
    const float* lb_b4    = (const float*)d_in[20];
    const float* lb_a4    = (const float*)d_in[21];
    const float* lb_w5    = (const float*)d_in[22];
    const float* lb_b5    = (const float*)d_in[23];
    const float* hb_gn_g  = (const float*)d_in[24];
    const float* hb_gn_b  = (const float*)d_in[25];
    const float* hb_w     = (const float*)d_in[26];
    const float* hb_b     = (const float*)d_in[27];
    const float* fu_w1    = (const float*)d_in[28];
    const float* fu_b1    = (const float*)d_in[29];
    const float* fu_gn_g  = (const float*)d_in[30];
    const float* fu_gn_b  = (const float*)d_in[31];
    const float* fu_w2    = (const float*)d_in[32];
    const float* fu_b2    = (const float*)d_in[33];
    float* out = (float*)d_out;

    // ws layout (bytes)
    const size_t O1B = (size_t)Nn*HW*128*2;     // 37,748,736  o1 bf16 [n][px][128]
    const size_t EB  = (size_t)Nn*HW*64*2;      // 18,874,368  bf16 [n][px][64]
    const size_t YB  = (size_t)Nn*16*HW*4;      // 9,437,184   f32 planar
    char* Wb = (char*)d_ws;
    unsigned short* o1       = (unsigned short*)Wb;               // [0, O1B)
    unsigned short* high     = (unsigned short*)Wb;               // aliases o1 (dead before fu1m writes)
    unsigned short* enh_low  = (unsigned short*)(Wb + O1B);
    unsigned short* enh_high = (unsigned short*)(Wb + O1B + EB);
    float* y1                = (float*)(Wb + O1B + 2*EB);
    float* y2                = (float*)(Wb + O1B + 2*EB + YB);
    unsigned short* g_wt     = (unsigned short*)(Wb + O1B + 2*EB + 2*YB); // 36864 ush
    unsigned short* g_wfu1   = g_wt + 36864;                              // 16384 ush
    unsigned short* g_wfu2   = g_wfu1 + 16384;                            // 8192 ush
    float* fp      = (float*)(g_wfu2 + 8192);
    float* fsm     = fp + 256;
    float* st_hb   = fsm + 2304;       // 16 groups * 32 floats (padded lines)
    float* st_o1   = st_hb + 512;      // 16 groups * 32 floats
    float* part_hb = st_o1 + 512;      // 576 * 8 floats
    float* part_o1 = part_hb + 4608;   // 1152 * 8 floats

    k_prep<<<496, 256, 0, stream>>>(hb_w, fu_w1, fu_w2, x, g_wt, g_wfu1, g_wfu2, fp);
    k_filter<<<Nn, 576, 0, stream>>>(fp, w_filter, gnf_g, gnf_b, fsm);
    k_lowhigh<<<Nn*144, 256, 0, stream>>>(x, fsm, lb_w1, lb_b1, lb_a1, high, y1, part_hb);
    k_redstats<<<16, 256, 0, stream>>>(part_hb, st_hb, 144);
    k_conv3m<<<Nn*144, 256, 0, stream>>>(high, st_hb, hb_gn_g, hb_gn_b, g_wt, hb_b, enh_high);
    k_dw_c<5><<<Nn*PIXBLK, 256, 0, stream>>>(y1, lb_dw1, lb_db1, lb_w2, lb_b2, lb_a2, y2);
    k_dw_c<1><<<Nn*PIXBLK, 256, 0, stream>>>(y2, lb_dw2, lb_db2, lb_w3, lb_b3, lb_a3, y1);
    k_dw3_final<<<Nn*PIXBLK, 256, 0, stream>>>(y1, lb_dw3, lb_db3, lb_w4, lb_b4, lb_a4,
                                               lb_w5, lb_b5, enh_low);
    k_fu1m<<<Nn*288, 256, 0, stream>>>(enh_low, enh_high, g_wfu1, fu_b1, o1, part_o1);
    k_redstats<<<16, 256, 0, stream>>>(part_o1, st_o1, 288);
    k_fu2m<<<Nn*288, 256, 0, stream>>>(o1, st_o1, fu_gn_g, fu_gn_b, g_wfu2, fu_b2, out);
}